// Round 9
// baseline (367.170 us; speedup 1.0000x reference)
//
#include <hip/hip_runtime.h>
#include <math.h>

// Sparse MHA encoder: B=4, S=1024, D=1024, H=16, dk=64.
// Numerics: the 0.09 threshold is a step function on first-pass softmax.
// Score path (Q/K projections + QK^T) stays split-bf16 (hi+lo, ~2^-18 rel
// err) -> E[mask flips] ~1e-4. Conversions are hoisted OUT of the GEMM loops
// into tiny pre-split kernels (R8 counter-proof: in-loop fp32->bf16 VALU
// ~= MFMA time per step, and redundant 8-32x across blocks).
// Post-mask paths (V-proj, PV, ctx, O-proj) are DIRECT bf16 (1 MFMA): cannot
// flip masks; adds ~3e-3 abs err (budget 28.75e-3).
// Pass B recomputes scores BIT-IDENTICALLY to pass A (same helper, same LDS).
// Uniform-row skip: row all-masked <=> rowmax < tau = log(0.09*Z); ~11/65536
// rows are non-uniform (5.1-sigma cut) -> pass B nearly free.

constexpr int D_MODEL = 1024;
constexpr int N_HEADS = 16;
constexpr int D_HEAD  = 64;
constexpr int SEQ     = 1024;
constexpr int BATCH   = 4;
constexpr float SPARSE_THRESH = 0.09f;

typedef short  bf16x8 __attribute__((ext_vector_type(8)));
typedef float  f32x4  __attribute__((ext_vector_type(4)));

__device__ __forceinline__ unsigned short f2bf_rne(float x) {
    unsigned u = __float_as_uint(x);
    u += 0x7FFFu + ((u >> 16) & 1u);          // round-to-nearest-even
    return (unsigned short)(u >> 16);
}
__device__ __forceinline__ float bf2f(unsigned short b) {
    return __uint_as_float(((unsigned)b) << 16);
}

// ============ pre-split converters ============
// f32 -> hi/lo bf16 planes (split) or hi-only. 8 elems/thread, exact-fit grids.
__global__ __launch_bounds__(256)
void conv_split2(const float* __restrict__ a, unsigned short* __restrict__ ah,
                 unsigned short* __restrict__ al, int na8,
                 const float* __restrict__ b, unsigned short* __restrict__ bh,
                 unsigned short* __restrict__ bl, int nb8)
{
    int i = blockIdx.x * 256 + threadIdx.x;
    const float* s; unsigned short *dh, *dl;
    if (i < na8) { s = a + (size_t)i * 8; dh = ah + (size_t)i * 8; dl = al + (size_t)i * 8; }
    else { i -= na8; if (i >= nb8) return;
           s = b + (size_t)i * 8; dh = bh + (size_t)i * 8; dl = bl + (size_t)i * 8; }
    const float4 x0 = ((const float4*)s)[0], x1 = ((const float4*)s)[1];
    const float xs[8] = {x0.x, x0.y, x0.z, x0.w, x1.x, x1.y, x1.z, x1.w};
    unsigned short h[8], l[8];
    #pragma unroll
    for (int e = 0; e < 8; ++e) {
        h[e] = f2bf_rne(xs[e]);
        l[e] = f2bf_rne(xs[e] - bf2f(h[e]));
    }
    *(uint4*)dh = *(const uint4*)h;
    *(uint4*)dl = *(const uint4*)l;
}

__global__ __launch_bounds__(256)
void conv_hi3(const float* __restrict__ a, unsigned short* __restrict__ ah, int na8,
              const float* __restrict__ b, unsigned short* __restrict__ bh, int nb8,
              const float* __restrict__ c, unsigned short* __restrict__ ch, int nc8)
{
    int i = blockIdx.x * 256 + threadIdx.x;
    const float* s; unsigned short* dh;
    if (i < na8) { s = a + (size_t)i * 8; dh = ah + (size_t)i * 8; }
    else if ((i -= na8) < nb8) { s = b + (size_t)i * 8; dh = bh + (size_t)i * 8; }
    else { i -= nb8; if (i >= nc8) return; s = c + (size_t)i * 8; dh = ch + (size_t)i * 8; }
    const float4 x0 = ((const float4*)s)[0], x1 = ((const float4*)s)[1];
    const float xs[8] = {x0.x, x0.y, x0.z, x0.w, x1.x, x1.y, x1.z, x1.w};
    unsigned short h[8];
    #pragma unroll
    for (int e = 0; e < 8; ++e) h[e] = f2bf_rne(xs[e]);
    *(uint4*)dh = *(const uint4*)h;
}

// ============ split-bf16 Q/K projection (pure MFMA, no in-loop conversion) ============
// C = A @ B^T + bias, A:[4096][1024] hi/lo bf16 planes, B:[1024][1024] planes.
// Output: hi/lo bf16 planes, head-split [B,H,S,dk], scaled by `scale`.
__global__ __launch_bounds__(256, 2)
void proj_qk(const unsigned short* __restrict__ Ah, const unsigned short* __restrict__ Al,
             const unsigned short* __restrict__ Bh, const unsigned short* __restrict__ Bl,
             const float* __restrict__ bias,
             unsigned short* __restrict__ Chi, unsigned short* __restrict__ Clo, float scale)
{
    __shared__ unsigned short A_h[128][40];
    __shared__ unsigned short A_l[128][40];
    __shared__ unsigned short B_h[128][40];
    __shared__ unsigned short B_l[128][40];

    const int K = D_MODEL;
    const int tid = threadIdx.x, lane = tid & 63;
    const int l15 = lane & 15, l4 = lane >> 4;
    const int wv = tid >> 6;
    const int wr = (wv >> 1) * 64, wc = (wv & 1) * 64;
    const int bm = blockIdx.y * 128, bn = blockIdx.x * 128;
    const int pr = tid >> 1, ph = (tid & 1) * 16;

    f32x4 acc[4][4];
    #pragma unroll
    for (int i = 0; i < 4; ++i)
        #pragma unroll
        for (int j = 0; j < 4; ++j) acc[i][j] = (f32x4){0.f, 0.f, 0.f, 0.f};

    const unsigned short* gah = Ah + (size_t)(bm + pr) * K + ph;
    const unsigned short* gal = Al + (size_t)(bm + pr) * K + ph;
    const unsigned short* gbh = Bh + (size_t)(bn + pr) * K + ph;
    const unsigned short* gbl = Bl + (size_t)(bn + pr) * K + ph;

    uint4 va[8];
    va[0] = *(const uint4*)&gah[0]; va[1] = *(const uint4*)&gah[8];
    va[2] = *(const uint4*)&gal[0]; va[3] = *(const uint4*)&gal[8];
    va[4] = *(const uint4*)&gbh[0]; va[5] = *(const uint4*)&gbh[8];
    va[6] = *(const uint4*)&gbl[0]; va[7] = *(const uint4*)&gbl[8];

    #pragma unroll 1
    for (int k0 = 0; k0 < K; k0 += 32) {
        __syncthreads();                 // prior frag reads done
        *(uint4*)&A_h[pr][ph] = va[0]; *(uint4*)&A_h[pr][ph + 8] = va[1];
        *(uint4*)&A_l[pr][ph] = va[2]; *(uint4*)&A_l[pr][ph + 8] = va[3];
        *(uint4*)&B_h[pr][ph] = va[4]; *(uint4*)&B_h[pr][ph + 8] = va[5];
        *(uint4*)&B_l[pr][ph] = va[6]; *(uint4*)&B_l[pr][ph + 8] = va[7];
        __syncthreads();                 // tile ready

        if (k0 + 32 < K) {               // issue next-step loads under MFMA
            const int o = k0 + 32;
            va[0] = *(const uint4*)&gah[o]; va[1] = *(const uint4*)&gah[o + 8];
            va[2] = *(const uint4*)&gal[o]; va[3] = *(const uint4*)&gal[o + 8];
            va[4] = *(const uint4*)&gbh[o]; va[5] = *(const uint4*)&gbh[o + 8];
            va[6] = *(const uint4*)&gbl[o]; va[7] = *(const uint4*)&gbl[o + 8];
        }

        bf16x8 ah[4], al4[4], bh4[4], bl4[4];
        #pragma unroll
        for (int i = 0; i < 4; ++i) {
            const int r = wr + i * 16 + l15;
            const int c = wc + i * 16 + l15;
            ah[i]  = *(const bf16x8*)&A_h[r][l4 * 8];
            al4[i] = *(const bf16x8*)&A_l[r][l4 * 8];
            bh4[i] = *(const bf16x8*)&B_h[c][l4 * 8];
            bl4[i] = *(const bf16x8*)&B_l[c][l4 * 8];
        }
        #pragma unroll
        for (int i = 0; i < 4; ++i)
            #pragma unroll
            for (int j = 0; j < 4; ++j) {
                acc[i][j] = __builtin_amdgcn_mfma_f32_16x16x32_bf16(ah[i],  bh4[j], acc[i][j], 0, 0, 0);
                acc[i][j] = __builtin_amdgcn_mfma_f32_16x16x32_bf16(ah[i],  bl4[j], acc[i][j], 0, 0, 0);
                acc[i][j] = __builtin_amdgcn_mfma_f32_16x16x32_bf16(al4[i], bh4[j], acc[i][j], 0, 0, 0);
            }
    }

    // epilogue: D row=(l>>4)*4+r, col=l&15; head-split hi/lo stores
    #pragma unroll
    for (int i = 0; i < 4; ++i)
        #pragma unroll
        for (int j = 0; j < 4; ++j) {
            const int rb = bm + wr + i * 16 + l4 * 4;
            const int c  = bn + wc + j * 16 + l15;
            const float bi = bias[c];
            #pragma unroll
            for (int r = 0; r < 4; ++r) {
                const float val = (acc[i][j][r] + bi) * scale;
                const unsigned short hu = f2bf_rne(val);
                const int mrow = rb + r;
                const int b = mrow >> 10, s = mrow & (SEQ - 1);
                const int h = c >> 6, d = c & (D_HEAD - 1);
                const size_t off = ((size_t)(b * N_HEADS + h) * SEQ + s) * D_HEAD + d;
                Chi[off] = hu;
                Clo[off] = f2bf_rne(val - bf2f(hu));
            }
        }
}

// ============ direct-bf16 V/O projection ============
// MODE 2: V -> bf16 plane TRANSPOSED [B,H,dk,S] (LDS bounce, 16B-run stores).
// MODE 0: O -> fp32 C[r*1024+c].
template <int MODE>
__global__ __launch_bounds__(256, 2)
void proj_vo(const unsigned short* __restrict__ Ah, const unsigned short* __restrict__ Bh,
             const float* __restrict__ bias, float* __restrict__ Cf,
             unsigned short* __restrict__ Cv, float scale)
{
    __shared__ unsigned short A_h[128][40];
    __shared__ unsigned short B_h[128][40];
    __shared__ unsigned short Tb[128][136];      // MODE2 bounce

    const int K = D_MODEL;
    const int tid = threadIdx.x, lane = tid & 63;
    const int l15 = lane & 15, l4 = lane >> 4;
    const int wv = tid >> 6;
    const int wr = (wv >> 1) * 64, wc = (wv & 1) * 64;
    const int bm = blockIdx.y * 128, bn = blockIdx.x * 128;
    const int pr = tid >> 1, ph = (tid & 1) * 16;

    f32x4 acc[4][4];
    #pragma unroll
    for (int i = 0; i < 4; ++i)
        #pragma unroll
        for (int j = 0; j < 4; ++j) acc[i][j] = (f32x4){0.f, 0.f, 0.f, 0.f};

    const unsigned short* gah = Ah + (size_t)(bm + pr) * K + ph;
    const unsigned short* gbh = Bh + (size_t)(bn + pr) * K + ph;

    uint4 va[4];
    va[0] = *(const uint4*)&gah[0]; va[1] = *(const uint4*)&gah[8];
    va[2] = *(const uint4*)&gbh[0]; va[3] = *(const uint4*)&gbh[8];

    #pragma unroll 1
    for (int k0 = 0; k0 < K; k0 += 32) {
        __syncthreads();
        *(uint4*)&A_h[pr][ph] = va[0]; *(uint4*)&A_h[pr][ph + 8] = va[1];
        *(uint4*)&B_h[pr][ph] = va[2]; *(uint4*)&B_h[pr][ph + 8] = va[3];
        __syncthreads();

        if (k0 + 32 < K) {
            const int o = k0 + 32;
            va[0] = *(const uint4*)&gah[o]; va[1] = *(const uint4*)&gah[o + 8];
            va[2] = *(const uint4*)&gbh[o]; va[3] = *(const uint4*)&gbh[o + 8];
        }

        bf16x8 ah[4], bh4[4];
        #pragma unroll
        for (int i = 0; i < 4; ++i) {
            ah[i]  = *(const bf16x8*)&A_h[wr + i * 16 + l15][l4 * 8];
            bh4[i] = *(const bf16x8*)&B_h[wc + i * 16 + l15][l4 * 8];
        }
        #pragma unroll
        for (int i = 0; i < 4; ++i)
            #pragma unroll
            for (int j = 0; j < 4; ++j)
                acc[i][j] = __builtin_amdgcn_mfma_f32_16x16x32_bf16(ah[i], bh4[j], acc[i][j], 0, 0, 0);
    }

    if (MODE == 2) {
        __syncthreads();
        #pragma unroll
        for (int i = 0; i < 4; ++i)
            #pragma unroll
            for (int j = 0; j < 4; ++j) {
                const int cl = wc + j * 16 + l15;
                const int sl = wr + i * 16 + l4 * 4;
                const float bi = bias[bn + cl];
                unsigned short h4[4];
                #pragma unroll
                for (int r = 0; r < 4; ++r)
                    h4[r] = f2bf_rne((acc[i][j][r] + bi) * scale);
                *(uint2*)&Tb[cl][sl] = *(const uint2*)&h4[0];
            }
        __syncthreads();
        const int cg = lane >> 4;
        const int sl = (lane & 15) * 8;
        const int bb = bm >> 10;
        const int sb = bm & (SEQ - 1);
        #pragma unroll
        for (int it = 0; it < 8; ++it) {
            const int c = wv * 32 + it * 4 + cg;
            unsigned short* dst = Cv + (((size_t)bb << 20) + (size_t)(bn + c) * SEQ + sb + sl);
            *(uint4*)dst = *(const uint4*)&Tb[c][sl];
        }
        return;
    }

    // MODE 0: fp32 row-major
    #pragma unroll
    for (int i = 0; i < 4; ++i)
        #pragma unroll
        for (int j = 0; j < 4; ++j) {
            const int rb = bm + wr + i * 16 + l4 * 4;
            const int c  = bn + wc + j * 16 + l15;
            const float bi = bias[c];
            #pragma unroll
            for (int r = 0; r < 4; ++r)
                Cf[(size_t)(rb + r) * D_MODEL + c] = acc[i][j][r] + bi;
        }
}

// ============ MFMA attention ============
__device__ __forceinline__ void score_from_lds(
    const unsigned short (* __restrict__ KH)[72], const unsigned short (* __restrict__ KL)[72],
    int l15, int l4, const bf16x8 (&qh)[2][2], const bf16x8 (&ql)[2][2], f32x4 acc[2][4])
{
    #pragma unroll
    for (int j = 0; j < 4; ++j) {
        const int row = l15 + 16 * j;
        const bf16x8 kh0 = *(const bf16x8*)&KH[row][l4 * 8];
        const bf16x8 kh1 = *(const bf16x8*)&KH[row][32 + l4 * 8];
        const bf16x8 kl0 = *(const bf16x8*)&KL[row][l4 * 8];
        const bf16x8 kl1 = *(const bf16x8*)&KL[row][32 + l4 * 8];
        #pragma unroll
        for (int st = 0; st < 2; ++st) {
            f32x4 a = (f32x4){0.f, 0.f, 0.f, 0.f};
            a = __builtin_amdgcn_mfma_f32_16x16x32_bf16(qh[st][0], kh0, a, 0, 0, 0);
            a = __builtin_amdgcn_mfma_f32_16x16x32_bf16(qh[st][0], kl0, a, 0, 0, 0);
            a = __builtin_amdgcn_mfma_f32_16x16x32_bf16(ql[st][0], kh0, a, 0, 0, 0);
            a = __builtin_amdgcn_mfma_f32_16x16x32_bf16(qh[st][1], kh1, a, 0, 0, 0);
            a = __builtin_amdgcn_mfma_f32_16x16x32_bf16(qh[st][1], kl1, a, 0, 0, 0);
            a = __builtin_amdgcn_mfma_f32_16x16x32_bf16(ql[st][1], kh1, a, 0, 0, 0);
            acc[st][j] = a;
        }
    }
}

// One block = 128 q of one (b,h): 4 waves x 32 q. K chunk double-buffered in
// LDS from hi/lo planes (no unpack VALU). ctx out: bf16-hi plane (O direct).
__global__ __launch_bounds__(256, 2)
void attn_mfma(const unsigned short* __restrict__ qhh, const unsigned short* __restrict__ qhl,
               const unsigned short* __restrict__ khh, const unsigned short* __restrict__ khl,
               const unsigned short* __restrict__ vt, unsigned short* __restrict__ ctxh)
{
    __shared__ unsigned short KHL[2][2][64][72];   // [buf][hi/lo][k][d]
    __shared__ unsigned short Wl[4][32][72];       // per-wave W bf16 [q][k]
    __shared__ float Pm[64][4];
    __shared__ float Vm[64];
    __shared__ int AnyNU;

    const int tid  = threadIdx.x;
    const int lane = tid & 63;
    const int wv   = tid >> 6;
    const int l15  = lane & 15, l4 = lane >> 4;
    const int bh   = blockIdx.x;                   // XCD locality: id%8 = bh%8
    const int b    = bh >> 4, h = bh & 15;
    const int q0   = blockIdx.y * 128 + wv * 32;

    // ---- Q fragments from hi/lo planes ----
    bf16x8 qh[2][2], ql[2][2];
    #pragma unroll
    for (int st = 0; st < 2; ++st) {
        const size_t qoff = ((size_t)bh * SEQ + q0 + st * 16 + l15) * D_HEAD + l4 * 8;
        #pragma unroll
        for (int ks = 0; ks < 2; ++ks) {
            qh[st][ks] = *(const bf16x8*)&qhh[qoff + ks * 32];
            ql[st][ks] = *(const bf16x8*)&qhl[qoff + ks * 32];
        }
    }

    const unsigned short* vtb = vt + (size_t)bh * D_HEAD * SEQ;

    // ---- vmean partials ----
    {
        const int d = tid >> 2, q4 = tid & 3;
        const unsigned short* vr = vtb + (size_t)d * SEQ + q4 * 256;
        float s0 = 0.f, s1 = 0.f, s2 = 0.f, s3 = 0.f;
        #pragma unroll 4
        for (int i = 0; i < 32; ++i) {
            bf16x8 v8 = *(const bf16x8*)&vr[i * 8];
            s0 += bf2f((unsigned short)v8[0]) + bf2f((unsigned short)v8[4]);
            s1 += bf2f((unsigned short)v8[1]) + bf2f((unsigned short)v8[5]);
            s2 += bf2f((unsigned short)v8[2]) + bf2f((unsigned short)v8[6]);
            s3 += bf2f((unsigned short)v8[3]) + bf2f((unsigned short)v8[7]);
        }
        Pm[d][q4] = (s0 + s1) + (s2 + s3);
        if (tid == 0) AnyNU = 0;
    }

    // staging: thread covers k-row sr, d-offset sd (16 elems per plane)
    const int sr = tid >> 2;
    const int sd = (tid & 3) * 16;
    const unsigned short* kbh = khh + (size_t)bh * SEQ * D_HEAD;
    const unsigned short* kbl = khl + (size_t)bh * SEQ * D_HEAD;

    {   // prologue: stage chunk 0 -> buf 0
        const size_t o = (size_t)sr * D_HEAD + sd;
        *(uint4*)&KHL[0][0][sr][sd]     = *(const uint4*)&kbh[o];
        *(uint4*)&KHL[0][0][sr][sd + 8] = *(const uint4*)&kbh[o + 8];
        *(uint4*)&KHL[0][1][sr][sd]     = *(const uint4*)&kbl[o];
        *(uint4*)&KHL[0][1][sr][sd + 8] = *(const uint4*)&kbl[o + 8];
    }
    __syncthreads();

    if (tid < 64)
        Vm[tid] = (Pm[tid][0] + Pm[tid][1] + Pm[tid][2] + Pm[tid][3]) * (1.f / 1024.f);

    float mloc[2][4], zloc[2][4];
    #pragma unroll
    for (int st = 0; st < 2; ++st)
        #pragma unroll
        for (int r = 0; r < 4; ++r) { mloc[st][r] = -1e30f; zloc[st][r] = 0.f; }

    int cur = 0;

    // ========== pass A: Z = sum(e^s), m = max(s) ==========
    #pragma unroll 1
    for (int c = 0; c < 16; ++c) {
        const int cn = (c + 1) & 15;
        const size_t o = ((size_t)cn * 64 + sr) * D_HEAD + sd;
        uint4 uh0 = *(const uint4*)&kbh[o], uh1 = *(const uint4*)&kbh[o + 8];
        uint4 ul0 = *(const uint4*)&kbl[o], ul1 = *(const uint4*)&kbl[o + 8];

        f32x4 acc[2][4];
        score_from_lds(KHL[cur][0], KHL[cur][1], l15, l4, qh, ql, acc);

        #pragma unroll
        for (int st = 0; st < 2; ++st)
            #pragma unroll
            for (int r = 0; r < 4; ++r) {
                const float a0 = acc[st][0][r], a1 = acc[st][1][r];
                const float a2 = acc[st][2][r], a3 = acc[st][3][r];
                mloc[st][r] = fmaxf(mloc[st][r], fmaxf(fmaxf(a0, a1), fmaxf(a2, a3)));
                zloc[st][r] += (__expf(a0) + __expf(a1)) + (__expf(a2) + __expf(a3));
            }

        const int nxt = cur ^ 1;
        *(uint4*)&KHL[nxt][0][sr][sd]     = uh0;
        *(uint4*)&KHL[nxt][0][sr][sd + 8] = uh1;
        *(uint4*)&KHL[nxt][1][sr][sd]     = ul0;
        *(uint4*)&KHL[nxt][1][sr][sd + 8] = ul1;
        __syncthreads();
        cur = nxt;
    }

    // ---- merge; tau test; uniform detect ----
    float taue[2][4];
    bool  unif[2][4];
    int mynu = 0;
    #pragma unroll
    for (int st = 0; st < 2; ++st)
        #pragma unroll
        for (int r = 0; r < 4; ++r) {
            float mm = mloc[st][r], zz = zloc[st][r];
            #pragma unroll
            for (int o = 1; o <= 8; o <<= 1) {
                mm = fmaxf(mm, __shfl_xor(mm, o, 16));
                zz += __shfl_xor(zz, o, 16);
            }
            const float tau = __logf(SPARSE_THRESH * zz);
            const bool uni = (mm < tau);
            unif[st][r] = uni;
            taue[st][r] = uni ? 3.0e38f : tau;
            mynu |= uni ? 0 : 1;
        }
    if (__any(mynu)) { if (lane == 0) atomicOr(&AnyNU, 1); }
    __syncthreads();
    const bool runB = (AnyNU != 0);

    float z2[2][4];
    f32x4 pv[2][4];
    #pragma unroll
    for (int st = 0; st < 2; ++st)
        #pragma unroll
        for (int r = 0; r < 4; ++r) { z2[st][r] = 0.f; pv[st][r] = (f32x4){0.f, 0.f, 0.f, 0.f}; }

    // ========== pass B: only if a non-uniform row exists ==========
    if (runB) {
        #pragma unroll 1
        for (int c = 0; c < 16; ++c) {
            const int cn = (c + 1) & 15;
            const size_t o = ((size_t)cn * 64 + sr) * D_HEAD + sd;
            uint4 uh0 = *(const uint4*)&kbh[o], uh1 = *(const uint4*)&kbh[o + 8];
            uint4 ul0 = *(const uint4*)&kbl[o], ul1 = *(const uint4*)&kbl[o + 8];

            f32x4 acc[2][4];
            score_from_lds(KHL[cur][0], KHL[cur][1], l15, l4, qh, ql, acc);  // bit-identical

            int any = 0;
            #pragma unroll
            for (int st = 0; st < 2; ++st)
                #pragma unroll
                for (int r = 0; r < 4; ++r) {
                    const float rmax = fmaxf(fmaxf(acc[st][0][r], acc[st][1][r]),
                                             fmaxf(acc[st][2][r], acc[st][3][r]));
                    any |= (rmax >= taue[st][r]) ? 1 : 0;
                }

            if (__any(any)) {
                #pragma unroll
                for (int st = 0; st < 2; ++st)
                    #pragma unroll
                    for (int j = 0; j < 4; ++j)
                        #pragma unroll
                        for (int r = 0; r < 4; ++r) {
                            const float a = acc[st][j][r];
                            const float w = (a >= taue[st][r]) ? __expf(a) : 0.f;
                            const unsigned short wb = f2bf_rne(w);
                            z2[st][r] += bf2f(wb);
                            Wl[wv][st * 16 + l4 * 4 + r][l15 + 16 * j] = wb;
                        }
                asm volatile("s_waitcnt lgkmcnt(0)" ::: "memory");
                __builtin_amdgcn_sched_barrier(0);

                bf16x8 wa[2][2];
                #pragma unroll
                for (int st = 0; st < 2; ++st)
                    #pragma unroll
                    for (int ks = 0; ks < 2; ++ks)
                        wa[st][ks] = *(const bf16x8*)&Wl[wv][st * 16 + l15][ks * 32 + l4 * 8];

                #pragma unroll
                for (int ds = 0; ds < 4; ++ds) {
                    const bf16x8 v0 = *(const bf16x8*)
                        &vtb[(size_t)(ds * 16 + l15) * SEQ + c * 64 + l4 * 8];
                    const bf16x8 v1 = *(const bf16x8*)
                        &vtb[(size_t)(ds * 16 + l15) * SEQ + c * 64 + 32 + l4 * 8];
                    #pragma unroll
                    for (int st = 0; st < 2; ++st) {
                        pv[st][ds] = __builtin_amdgcn_mfma_f32_16x16x32_bf16(wa[st][0], v0, pv[st][ds], 0, 0, 0);
                        pv[st][ds] = __builtin_amdgcn_mfma_f32_16x16x32_bf16(wa[st][1], v1, pv[st][ds], 0, 0, 0);
                    }
                }
            }

            const int nxt = cur ^ 1;
            *(uint4*)&KHL[nxt][0][sr][sd]     = uh0;
            *(uint4*)&KHL[nxt][0][sr][sd + 8] = uh1;
            *(uint4*)&KHL[nxt][1][sr][sd]     = ul0;
            *(uint4*)&KHL[nxt][1][sr][sd + 8] = ul1;
            __syncthreads();
            cur = nxt;
        }

        #pragma unroll
        for (int st = 0; st < 2; ++st)
            #pragma unroll
            for (int r = 0; r < 4; ++r) {
                #pragma unroll
                for (int o = 1; o <= 8; o <<= 1) z2[st][r] += __shfl_xor(z2[st][r], o, 16);
            }
    }

    // ---- epilogue: select vmean vs pv/z2; bounce; bf16-hi ctx plane ----
    float* Tw = (float*)&KHL[0][0][0][0] + wv * 2176;   // per-wave [32][68] f32
    #pragma unroll
    for (int st = 0; st < 2; ++st)
        #pragma unroll
        for (int r = 0; r < 4; ++r) {
            const float inv = unif[st][r] ? 0.f : (1.f / z2[st][r]);
            const int row = st * 16 + l4 * 4 + r;
            #pragma unroll
            for (int ds = 0; ds < 4; ++ds) {
                const int d = ds * 16 + l15;
                Tw[row * 68 + d] = unif[st][r] ? Vm[d] : pv[st][ds][r] * inv;
            }
        }
    asm volatile("s_waitcnt lgkmcnt(0)" ::: "memory");
    __builtin_amdgcn_sched_barrier(0);

    const int rr = lane >> 1, seg = lane & 1;
    const size_t gbase = ((size_t)b * SEQ + q0 + rr) * D_MODEL + h * D_HEAD + seg * 32;
    #pragma unroll
    for (int u2 = 0; u2 < 8; ++u2) {
        const float4 t = *(const float4*)&Tw[rr * 68 + seg * 32 + u2 * 4];
        unsigned short h4[4] = {f2bf_rne(t.x), f2bf_rne(t.y), f2bf_rne(t.z), f2bf_rne(t.w)};
        *(uint2*)&ctxh[gbase + u2 * 4] = *(const uint2*)h4;
    }
}

extern "C" void kernel_launch(void* const* d_in, const int* in_sizes, int n_in,
                              void* d_out, int out_size, void* d_ws, size_t ws_size,
                              hipStream_t stream)
{
    const float* q  = (const float*)d_in[0];
    const float* k  = (const float*)d_in[1];
    const float* v  = (const float*)d_in[2];
    const float* Wq = (const float*)d_in[3];
    const float* bq = (const float*)d_in[4];
    const float* Wk = (const float*)d_in[5];
    const float* bk = (const float*)d_in[6];
    const float* Wv = (const float*)d_in[7];
    const float* bv = (const float*)d_in[8];
    const float* Wo = (const float*)d_in[9];
    const float* bo = (const float*)d_in[10];
    float* out = (float*)d_out;

    // workspace (62 MiB), slot-reused:
    //  [0..8M)   Xh  (input hi; later ctx_hi)      [8..16M)  Xl (input lo)
    //  [16..18M) Wh   [18..20M) Wlp   [20..22M) Woh
    //  [22..30M) qh_hi [30..38M) qh_lo [38..46M) kh_hi [46..54M) kh_lo
    //  [54..62M) vt
    const size_t MB = 1 << 20;
    char* w = (char*)d_ws;
    unsigned short* Xh  = (unsigned short*)(w);
    unsigned short* Xl  = (unsigned short*)(w + 8 * MB);
    unsigned short* Wh  = (unsigned short*)(w + 16 * MB);
    unsigned short* Wlp = (unsigned short*)(w + 18 * MB);
    unsigned short* Woh = (unsigned short*)(w + 20 * MB);
    unsigned short* qhh = (unsigned short*)(w + 22 * MB);
    unsigned short* qhl = (unsigned short*)(w + 30 * MB);
    unsigned short* khh = (unsigned short*)(w + 38 * MB);
    unsigned short* khl = (unsigned short*)(w + 46 * MB);
    unsigned short* vt  = (unsigned short*)(w + 54 * MB);
    unsigned short* ctxh = Xh;                    // alias: Xh dead after V-proj

    const int NA8 = (BATCH * SEQ * D_MODEL) / 8;  // 524288
    const int NW8 = (D_MODEL * D_MODEL) / 8;      // 131072
    dim3 gemmGrid(8, 32);

    conv_split2<<<(NA8 + NW8) / 256, 256, 0, stream>>>(q, Xh, Xl, NA8, Wq, Wh, Wlp, NW8);
    proj_qk<<<gemmGrid, 256, 0, stream>>>(Xh, Xl, Wh, Wlp, bq, qhh, qhl, 0.125f);

    conv_split2<<<(NA8 + NW8) / 256, 256, 0, stream>>>(k, Xh, Xl, NA8, Wk, Wh, Wlp, NW8);
    proj_qk<<<gemmGrid, 256, 0, stream>>>(Xh, Xl, Wh, Wlp, bk, khh, khl, 1.0f);

    conv_hi3<<<(NA8 + 2 * NW8) / 256, 256, 0, stream>>>(v, Xh, NA8, Wv, Wh, NW8, Wo, Woh, NW8);
    proj_vo<2><<<gemmGrid, 256, 0, stream>>>(Xh, Wh, bv, nullptr, vt, 1.0f);

    attn_mfma<<<dim3(BATCH * N_HEADS, SEQ / 128), 256, 0, stream>>>(qhh, qhl, khh, khl, vt, ctxh);

    proj_vo<0><<<gemmGrid, 256, 0, stream>>>(ctxh, Woh, bo, out, nullptr, 1.0f);
}

// Round 10
// 354.391 us; speedup vs baseline: 1.0361x; 1.0361x over previous
//
#include <hip/hip_runtime.h>
#include <math.h>

// Sparse MHA encoder: B=4, S=1024, D=1024, H=16, dk=64.
// Numerics: the 0.09 threshold is a step function on first-pass softmax.
// Score path (Q/K projections + QK^T) is split-bf16 (hi+lo, ~2^-18 rel err)
// -> E[mask flips] ~1e-4. Conversions hoisted into pre-split kernels.
// Post-mask paths (V-proj, PV, ctx, O-proj) are direct bf16: cannot flip
// masks; total abs err ~8e-3 vs 28.75e-3 budget.
// Pass B recomputes scores BIT-IDENTICALLY to pass A (same helper, same LDS).
// Uniform-row skip: row all-masked <=> rowmax < tau = log(0.09*Z).
// R10 (this round): GEMMs go 512-thread (2 waves/SIMD overlap; R9 proof:
// proj_qk 90% stalled at 1 wave/SIMD), grid (32,8) so same-A-panel blocks
// share an XCD (FETCH 70MB = 3.5x A re-fetch), packed-u32 Q/K epilogue
// (R9 WRITE 90MB = 5.6x amplification from dual-plane 2B scalar stores).

constexpr int D_MODEL = 1024;
constexpr int N_HEADS = 16;
constexpr int D_HEAD  = 64;
constexpr int SEQ     = 1024;
constexpr int BATCH   = 4;
constexpr float SPARSE_THRESH = 0.09f;

typedef short  bf16x8 __attribute__((ext_vector_type(8)));
typedef float  f32x4  __attribute__((ext_vector_type(4)));

__device__ __forceinline__ unsigned short f2bf_rne(float x) {
    unsigned u = __float_as_uint(x);
    u += 0x7FFFu + ((u >> 16) & 1u);          // round-to-nearest-even
    return (unsigned short)(u >> 16);
}
__device__ __forceinline__ float bf2f(unsigned short b) {
    return __uint_as_float(((unsigned)b) << 16);
}

union BF8 { unsigned u[4]; bf16x8 v; };

// 8 packed words (hi<<16|lo) -> hi bf16x8 + lo bf16x8
__device__ __forceinline__ void unpack_pair(const unsigned* u, bf16x8& hi, bf16x8& lo) {
    BF8 h, l;
    #pragma unroll
    for (int p = 0; p < 4; ++p) {
        h.u[p] = (u[2 * p] >> 16)      | (u[2 * p + 1] & 0xFFFF0000u);
        l.u[p] = (u[2 * p] & 0xFFFFu)  | (u[2 * p + 1] << 16);
    }
    hi = h.v; lo = l.v;
}

// ============ pre-split converters ============
__global__ __launch_bounds__(256)
void conv_split2(const float* __restrict__ a, unsigned short* __restrict__ ah,
                 unsigned short* __restrict__ al, int na8,
                 const float* __restrict__ b, unsigned short* __restrict__ bh,
                 unsigned short* __restrict__ bl, int nb8)
{
    int i = blockIdx.x * 256 + threadIdx.x;
    const float* s; unsigned short *dh, *dl;
    if (i < na8) { s = a + (size_t)i * 8; dh = ah + (size_t)i * 8; dl = al + (size_t)i * 8; }
    else { i -= na8; if (i >= nb8) return;
           s = b + (size_t)i * 8; dh = bh + (size_t)i * 8; dl = bl + (size_t)i * 8; }
    const float4 x0 = ((const float4*)s)[0], x1 = ((const float4*)s)[1];
    const float xs[8] = {x0.x, x0.y, x0.z, x0.w, x1.x, x1.y, x1.z, x1.w};
    unsigned short h[8], l[8];
    #pragma unroll
    for (int e = 0; e < 8; ++e) {
        h[e] = f2bf_rne(xs[e]);
        l[e] = f2bf_rne(xs[e] - bf2f(h[e]));
    }
    *(uint4*)dh = *(const uint4*)h;
    *(uint4*)dl = *(const uint4*)l;
}

__global__ __launch_bounds__(256)
void conv_hi3(const float* __restrict__ a, unsigned short* __restrict__ ah, int na8,
              const float* __restrict__ b, unsigned short* __restrict__ bh, int nb8,
              const float* __restrict__ c, unsigned short* __restrict__ ch, int nc8)
{
    int i = blockIdx.x * 256 + threadIdx.x;
    const float* s; unsigned short* dh;
    if (i < na8) { s = a + (size_t)i * 8; dh = ah + (size_t)i * 8; }
    else if ((i -= na8) < nb8) { s = b + (size_t)i * 8; dh = bh + (size_t)i * 8; }
    else { i -= nb8; if (i >= nc8) return; s = c + (size_t)i * 8; dh = ch + (size_t)i * 8; }
    const float4 x0 = ((const float4*)s)[0], x1 = ((const float4*)s)[1];
    const float xs[8] = {x0.x, x0.y, x0.z, x0.w, x1.x, x1.y, x1.z, x1.w};
    unsigned short h[8];
    #pragma unroll
    for (int e = 0; e < 8; ++e) h[e] = f2bf_rne(xs[e]);
    *(uint4*)dh = *(const uint4*)h;
}

// ============ split-bf16 Q/K projection, 512 threads (8 waves, 2/SIMD) ============
// C = A @ B^T + bias. Tile 128x128, BK=32; wave = 64x32 (2x4 wave grid).
// Output: PACKED u32 (hi<<16|lo), head-split [B,H,S,dk], scaled.
// Grid (32,8): x=bm -> linear id % 8 = bm%8 -> same-A-panel blocks on one XCD.
__global__ __launch_bounds__(512, 2)
void proj_qk(const unsigned short* __restrict__ Ah, const unsigned short* __restrict__ Al,
             const unsigned short* __restrict__ Bh, const unsigned short* __restrict__ Bl,
             const float* __restrict__ bias, unsigned* __restrict__ Cp, float scale)
{
    __shared__ unsigned short A_h[128][40];
    __shared__ unsigned short A_l[128][40];
    __shared__ unsigned short B_h[128][40];
    __shared__ unsigned short B_l[128][40];

    const int K = D_MODEL;
    const int tid = threadIdx.x, lane = tid & 63;
    const int l15 = lane & 15, l4 = lane >> 4;
    const int wv = tid >> 6;                       // 0..7
    const int wr = (wv >> 2) * 64, wc = (wv & 3) * 32;
    const int bm = blockIdx.x * 128, bn = blockIdx.y * 128;
    const int pr = tid >> 2, ph = (tid & 3) * 8;   // staging: row, ushort col

    f32x4 acc[4][2];
    #pragma unroll
    for (int i = 0; i < 4; ++i)
        #pragma unroll
        for (int j = 0; j < 2; ++j) acc[i][j] = (f32x4){0.f, 0.f, 0.f, 0.f};

    const unsigned short* gah = Ah + (size_t)(bm + pr) * K + ph;
    const unsigned short* gal = Al + (size_t)(bm + pr) * K + ph;
    const unsigned short* gbh = Bh + (size_t)(bn + pr) * K + ph;
    const unsigned short* gbl = Bl + (size_t)(bn + pr) * K + ph;

    uint4 va[4];
    va[0] = *(const uint4*)&gah[0];
    va[1] = *(const uint4*)&gal[0];
    va[2] = *(const uint4*)&gbh[0];
    va[3] = *(const uint4*)&gbl[0];

    #pragma unroll 1
    for (int k0 = 0; k0 < K; k0 += 32) {
        __syncthreads();
        *(uint4*)&A_h[pr][ph] = va[0];
        *(uint4*)&A_l[pr][ph] = va[1];
        *(uint4*)&B_h[pr][ph] = va[2];
        *(uint4*)&B_l[pr][ph] = va[3];
        __syncthreads();

        if (k0 + 32 < K) {
            const int o = k0 + 32;
            va[0] = *(const uint4*)&gah[o];
            va[1] = *(const uint4*)&gal[o];
            va[2] = *(const uint4*)&gbh[o];
            va[3] = *(const uint4*)&gbl[o];
        }

        bf16x8 ah[4], al4[4], bh4[2], bl4[2];
        #pragma unroll
        for (int i = 0; i < 4; ++i) {
            ah[i]  = *(const bf16x8*)&A_h[wr + i * 16 + l15][l4 * 8];
            al4[i] = *(const bf16x8*)&A_l[wr + i * 16 + l15][l4 * 8];
        }
        #pragma unroll
        for (int j = 0; j < 2; ++j) {
            bh4[j] = *(const bf16x8*)&B_h[wc + j * 16 + l15][l4 * 8];
            bl4[j] = *(const bf16x8*)&B_l[wc + j * 16 + l15][l4 * 8];
        }
        #pragma unroll
        for (int i = 0; i < 4; ++i)
            #pragma unroll
            for (int j = 0; j < 2; ++j) {
                acc[i][j] = __builtin_amdgcn_mfma_f32_16x16x32_bf16(ah[i],  bh4[j], acc[i][j], 0, 0, 0);
                acc[i][j] = __builtin_amdgcn_mfma_f32_16x16x32_bf16(ah[i],  bl4[j], acc[i][j], 0, 0, 0);
                acc[i][j] = __builtin_amdgcn_mfma_f32_16x16x32_bf16(al4[i], bh4[j], acc[i][j], 0, 0, 0);
            }
    }

    // epilogue: packed u32, head-split; per (i,j,r) a 64B contiguous run
    #pragma unroll
    for (int i = 0; i < 4; ++i)
        #pragma unroll
        for (int j = 0; j < 2; ++j) {
            const int rb = bm + wr + i * 16 + l4 * 4;
            const int c  = bn + wc + j * 16 + l15;
            const float bi = bias[c];
            const int h = c >> 6, d = c & (D_HEAD - 1);
            #pragma unroll
            for (int r = 0; r < 4; ++r) {
                const float val = (acc[i][j][r] + bi) * scale;
                const unsigned short hu = f2bf_rne(val);
                const unsigned short lu = f2bf_rne(val - bf2f(hu));
                const int mrow = rb + r;
                const int b = mrow >> 10, s = mrow & (SEQ - 1);
                Cp[((size_t)(b * N_HEADS + h) * SEQ + s) * D_HEAD + d] =
                    ((unsigned)hu << 16) | lu;
            }
        }
}

// ============ direct-bf16 V/O projection, 512 threads ============
// MODE 2: V -> bf16 plane TRANSPOSED [B,H,dk,S] (LDS bounce, 256B runs).
// MODE 0: O -> fp32 C[r*1024+c].
template <int MODE>
__global__ __launch_bounds__(512, 2)
void proj_vo(const unsigned short* __restrict__ Ah, const unsigned short* __restrict__ Bh,
             const float* __restrict__ bias, float* __restrict__ Cf,
             unsigned short* __restrict__ Cv, float scale)
{
    __shared__ unsigned short A_h[128][40];
    __shared__ unsigned short B_h[128][40];
    __shared__ unsigned short Tb[128][136];        // MODE2 bounce

    const int K = D_MODEL;
    const int tid = threadIdx.x, lane = tid & 63;
    const int l15 = lane & 15, l4 = lane >> 4;
    const int wv = tid >> 6;
    const int wr = (wv >> 2) * 64, wc = (wv & 3) * 32;
    const int bm = blockIdx.x * 128, bn = blockIdx.y * 128;
    const int pr = tid >> 2, ph = (tid & 3) * 8;

    f32x4 acc[4][2];
    #pragma unroll
    for (int i = 0; i < 4; ++i)
        #pragma unroll
        for (int j = 0; j < 2; ++j) acc[i][j] = (f32x4){0.f, 0.f, 0.f, 0.f};

    const unsigned short* gah = Ah + (size_t)(bm + pr) * K + ph;
    const unsigned short* gbh = Bh + (size_t)(bn + pr) * K + ph;

    uint4 va[2];
    va[0] = *(const uint4*)&gah[0];
    va[1] = *(const uint4*)&gbh[0];

    #pragma unroll 1
    for (int k0 = 0; k0 < K; k0 += 32) {
        __syncthreads();
        *(uint4*)&A_h[pr][ph] = va[0];
        *(uint4*)&B_h[pr][ph] = va[1];
        __syncthreads();

        if (k0 + 32 < K) {
            const int o = k0 + 32;
            va[0] = *(const uint4*)&gah[o];
            va[1] = *(const uint4*)&gbh[o];
        }

        bf16x8 ah[4], bh4[2];
        #pragma unroll
        for (int i = 0; i < 4; ++i)
            ah[i] = *(const bf16x8*)&A_h[wr + i * 16 + l15][l4 * 8];
        #pragma unroll
        for (int j = 0; j < 2; ++j)
            bh4[j] = *(const bf16x8*)&B_h[wc + j * 16 + l15][l4 * 8];
        #pragma unroll
        for (int i = 0; i < 4; ++i)
            #pragma unroll
            for (int j = 0; j < 2; ++j)
                acc[i][j] = __builtin_amdgcn_mfma_f32_16x16x32_bf16(ah[i], bh4[j], acc[i][j], 0, 0, 0);
    }

    if (MODE == 2) {
        __syncthreads();
        #pragma unroll
        for (int i = 0; i < 4; ++i)
            #pragma unroll
            for (int j = 0; j < 2; ++j) {
                const int cl = wc + j * 16 + l15;
                const int sl = wr + i * 16 + l4 * 4;
                const float bi = bias[bn + cl];
                unsigned short h4[4];
                #pragma unroll
                for (int r = 0; r < 4; ++r)
                    h4[r] = f2bf_rne((acc[i][j][r] + bi) * scale);
                *(uint2*)&Tb[cl][sl] = *(const uint2*)&h4[0];
            }
        __syncthreads();
        // thread t: col c = t>>2, seg = t&3; 64B contiguous per thread,
        // 4 threads cover a full 256B (h,s)-run
        const int c = tid >> 2, seg = tid & 3;
        const int bb = bm >> 10, sb = bm & (SEQ - 1);
        unsigned short* dst = Cv + (((size_t)bb << 20) + (size_t)(bn + c) * SEQ + sb + seg * 32);
        #pragma unroll
        for (int u = 0; u < 4; ++u)
            *(uint4*)&dst[u * 8] = *(const uint4*)&Tb[c][seg * 32 + u * 8];
        return;
    }

    // MODE 0: fp32 row-major, 64B runs
    #pragma unroll
    for (int i = 0; i < 4; ++i)
        #pragma unroll
        for (int j = 0; j < 2; ++j) {
            const int rb = bm + wr + i * 16 + l4 * 4;
            const int c  = bn + wc + j * 16 + l15;
            const float bi = bias[c];
            #pragma unroll
            for (int r = 0; r < 4; ++r)
                Cf[(size_t)(rb + r) * D_MODEL + c] = acc[i][j][r] + bi;
        }
}

// ============ MFMA attention ============
__device__ __forceinline__ void score_from_lds(
    const unsigned short (* __restrict__ KH)[72], const unsigned short (* __restrict__ KL)[72],
    int l15, int l4, const bf16x8 (&qh)[2][2], const bf16x8 (&ql)[2][2], f32x4 acc[2][4])
{
    #pragma unroll
    for (int j = 0; j < 4; ++j) {
        const int row = l15 + 16 * j;
        const bf16x8 kh0 = *(const bf16x8*)&KH[row][l4 * 8];
        const bf16x8 kh1 = *(const bf16x8*)&KH[row][32 + l4 * 8];
        const bf16x8 kl0 = *(const bf16x8*)&KL[row][l4 * 8];
        const bf16x8 kl1 = *(const bf16x8*)&KL[row][32 + l4 * 8];
        #pragma unroll
        for (int st = 0; st < 2; ++st) {
            f32x4 a = (f32x4){0.f, 0.f, 0.f, 0.f};
            a = __builtin_amdgcn_mfma_f32_16x16x32_bf16(qh[st][0], kh0, a, 0, 0, 0);
            a = __builtin_amdgcn_mfma_f32_16x16x32_bf16(qh[st][0], kl0, a, 0, 0, 0);
            a = __builtin_amdgcn_mfma_f32_16x16x32_bf16(ql[st][0], kh0, a, 0, 0, 0);
            a = __builtin_amdgcn_mfma_f32_16x16x32_bf16(qh[st][1], kh1, a, 0, 0, 0);
            a = __builtin_amdgcn_mfma_f32_16x16x32_bf16(qh[st][1], kl1, a, 0, 0, 0);
            a = __builtin_amdgcn_mfma_f32_16x16x32_bf16(ql[st][1], kh1, a, 0, 0, 0);
            acc[st][j] = a;
        }
    }
}

// One block = 128 q of one (b,h): 4 waves x 32 q. K chunk double-buffered in
// LDS from the PACKED plane (unpack during staging — R7-measured free).
__global__ __launch_bounds__(256, 2)
void attn_mfma(const unsigned* __restrict__ qp, const unsigned* __restrict__ kp,
               const unsigned short* __restrict__ vt, unsigned short* __restrict__ ctxh)
{
    __shared__ unsigned short KHL[2][2][64][72];   // [buf][hi/lo][k][d]
    __shared__ unsigned short Wl[4][32][72];       // per-wave W bf16 [q][k]
    __shared__ float Pm[64][4];
    __shared__ float Vm[64];
    __shared__ int AnyNU;

    const int tid  = threadIdx.x;
    const int lane = tid & 63;
    const int wv   = tid >> 6;
    const int l15  = lane & 15, l4 = lane >> 4;
    const int bh   = blockIdx.x;                   // XCD locality: id%8 = bh%8
    const int b    = bh >> 4, h = bh & 15;
    const int q0   = blockIdx.y * 128 + wv * 32;

    // ---- Q fragments (packed -> hi/lo) ----
    bf16x8 qh[2][2], ql[2][2];
    #pragma unroll
    for (int st = 0; st < 2; ++st) {
        const unsigned* qrow = qp + ((size_t)bh * SEQ + q0 + st * 16 + l15) * D_HEAD;
        #pragma unroll
        for (int ks = 0; ks < 2; ++ks) {
            unsigned u[8];
            *(uint4*)&u[0] = *(const uint4*)&qrow[ks * 32 + l4 * 8];
            *(uint4*)&u[4] = *(const uint4*)&qrow[ks * 32 + l4 * 8 + 4];
            unpack_pair(u, qh[st][ks], ql[st][ks]);
        }
    }

    const unsigned short* vtb = vt + (size_t)bh * D_HEAD * SEQ;

    // ---- vmean partials ----
    {
        const int d = tid >> 2, q4 = tid & 3;
        const unsigned short* vr = vtb + (size_t)d * SEQ + q4 * 256;
        float s0 = 0.f, s1 = 0.f, s2 = 0.f, s3 = 0.f;
        #pragma unroll 4
        for (int i = 0; i < 32; ++i) {
            bf16x8 v8 = *(const bf16x8*)&vr[i * 8];
            s0 += bf2f((unsigned short)v8[0]) + bf2f((unsigned short)v8[4]);
            s1 += bf2f((unsigned short)v8[1]) + bf2f((unsigned short)v8[5]);
            s2 += bf2f((unsigned short)v8[2]) + bf2f((unsigned short)v8[6]);
            s3 += bf2f((unsigned short)v8[3]) + bf2f((unsigned short)v8[7]);
        }
        Pm[d][q4] = (s0 + s1) + (s2 + s3);
        if (tid == 0) AnyNU = 0;
    }

    // staging: thread covers k-row sr, packed-word offset sd*? (16 words)
    const int sr = tid >> 2;
    const int sd = (tid & 3) * 16;
    const unsigned* kpb = kp + (size_t)bh * SEQ * D_HEAD;

    {   // prologue: stage chunk 0 -> buf 0 (unpack packed words)
        unsigned u[16];
        const unsigned* src = kpb + (size_t)sr * D_HEAD + sd;
        #pragma unroll
        for (int g = 0; g < 4; ++g) *(uint4*)&u[g * 4] = *(const uint4*)&src[g * 4];
        bf16x8 h0, l0, h1, l1;
        unpack_pair(&u[0], h0, l0);
        unpack_pair(&u[8], h1, l1);
        *(bf16x8*)&KHL[0][0][sr][sd]     = h0;
        *(bf16x8*)&KHL[0][0][sr][sd + 8] = h1;
        *(bf16x8*)&KHL[0][1][sr][sd]     = l0;
        *(bf16x8*)&KHL[0][1][sr][sd + 8] = l1;
    }
    __syncthreads();

    if (tid < 64)
        Vm[tid] = (Pm[tid][0] + Pm[tid][1] + Pm[tid][2] + Pm[tid][3]) * (1.f / 1024.f);

    float mloc[2][4], zloc[2][4];
    #pragma unroll
    for (int st = 0; st < 2; ++st)
        #pragma unroll
        for (int r = 0; r < 4; ++r) { mloc[st][r] = -1e30f; zloc[st][r] = 0.f; }

    int cur = 0;

    // ========== pass A: Z = sum(e^s), m = max(s) ==========
    #pragma unroll 1
    for (int c = 0; c < 16; ++c) {
        unsigned u[16];                             // stage next chunk (issue early)
        const int cn = (c + 1) & 15;
        const unsigned* src = kpb + ((size_t)cn * 64 + sr) * D_HEAD + sd;
        #pragma unroll
        for (int g = 0; g < 4; ++g) *(uint4*)&u[g * 4] = *(const uint4*)&src[g * 4];

        f32x4 acc[2][4];
        score_from_lds(KHL[cur][0], KHL[cur][1], l15, l4, qh, ql, acc);

        #pragma unroll
        for (int st = 0; st < 2; ++st)
            #pragma unroll
            for (int r = 0; r < 4; ++r) {
                const float a0 = acc[st][0][r], a1 = acc[st][1][r];
                const float a2 = acc[st][2][r], a3 = acc[st][3][r];
                mloc[st][r] = fmaxf(mloc[st][r], fmaxf(fmaxf(a0, a1), fmaxf(a2, a3)));
                zloc[st][r] += (__expf(a0) + __expf(a1)) + (__expf(a2) + __expf(a3));
            }

        bf16x8 h0, l0, h1, l1;                      // write staged chunk (late)
        unpack_pair(&u[0], h0, l0);
        unpack_pair(&u[8], h1, l1);
        const int nxt = cur ^ 1;
        *(bf16x8*)&KHL[nxt][0][sr][sd]     = h0;
        *(bf16x8*)&KHL[nxt][0][sr][sd + 8] = h1;
        *(bf16x8*)&KHL[nxt][1][sr][sd]     = l0;
        *(bf16x8*)&KHL[nxt][1][sr][sd + 8] = l1;
        __syncthreads();
        cur = nxt;
    }

    // ---- merge; tau test; uniform detect ----
    float taue[2][4];
    bool  unif[2][4];
    int mynu = 0;
    #pragma unroll
    for (int st = 0; st < 2; ++st)
        #pragma unroll
        for (int r = 0; r < 4; ++r) {
            float mm = mloc[st][r], zz = zloc[st][r];
            #pragma unroll
            for (int o = 1; o <= 8; o <<= 1) {
                mm = fmaxf(mm, __shfl_xor(mm, o, 16));
                zz += __shfl_xor(zz, o, 16);
            }
            const float tau = __logf(SPARSE_THRESH * zz);
            const bool uni = (mm < tau);
            unif[st][r] = uni;
            taue[st][r] = uni ? 3.0e38f : tau;
            mynu |= uni ? 0 : 1;
        }
    if (__any(mynu)) { if (lane == 0) atomicOr(&AnyNU, 1); }
    __syncthreads();
    const bool runB = (AnyNU != 0);

    float z2[2][4];
    f32x4 pv[2][4];
    #pragma unroll
    for (int st = 0; st < 2; ++st)
        #pragma unroll
        for (int r = 0; r < 4; ++r) { z2[st][r] = 0.f; pv[st][r] = (f32x4){0.f, 0.f, 0.f, 0.f}; }

    // ========== pass B: only if a non-uniform row exists ==========
    if (runB) {
        #pragma unroll 1
        for (int c = 0; c < 16; ++c) {
            unsigned u[16];
            const int cn = (c + 1) & 15;
            const unsigned* src = kpb + ((size_t)cn * 64 + sr) * D_HEAD + sd;
            #pragma unroll
            for (int g = 0; g < 4; ++g) *(uint4*)&u[g * 4] = *(const uint4*)&src[g * 4];

            f32x4 acc[2][4];
            score_from_lds(KHL[cur][0], KHL[cur][1], l15, l4, qh, ql, acc);  // bit-identical

            int any = 0;
            #pragma unroll
            for (int st = 0; st < 2; ++st)
                #pragma unroll
                for (int r = 0; r < 4; ++r) {
                    const float rmax = fmaxf(fmaxf(acc[st][0][r], acc[st][1][r]),
                                             fmaxf(acc[st][2][r], acc[st][3][r]));
                    any |= (rmax >= taue[st][r]) ? 1 : 0;
                }

            if (__any(any)) {
                #pragma unroll
                for (int st = 0; st < 2; ++st)
                    #pragma unroll
                    for (int j = 0; j < 4; ++j)
                        #pragma unroll
                        for (int r = 0; r < 4; ++r) {
                            const float a = acc[st][j][r];
                            const float w = (a >= taue[st][r]) ? __expf(a) : 0.f;
                            const unsigned short wb = f2bf_rne(w);
                            z2[st][r] += bf2f(wb);
                            Wl[wv][st * 16 + l4 * 4 + r][l15 + 16 * j] = wb;
                        }
                asm volatile("s_waitcnt lgkmcnt(0)" ::: "memory");
                __builtin_amdgcn_sched_barrier(0);

                bf16x8 wa[2][2];
                #pragma unroll
                for (int st = 0; st < 2; ++st)
                    #pragma unroll
                    for (int ks = 0; ks < 2; ++ks)
                        wa[st][ks] = *(const bf16x8*)&Wl[wv][st * 16 + l15][ks * 32 + l4 * 8];

                #pragma unroll
                for (int ds = 0; ds < 4; ++ds) {
                    const bf16x8 v0 = *(const bf16x8*)
                        &vtb[(size_t)(ds * 16 + l15) * SEQ + c * 64 + l4 * 8];
                    const bf16x8 v1 = *(const bf16x8*)
                        &vtb[(size_t)(ds * 16 + l15) * SEQ + c * 64 + 32 + l4 * 8];
                    #pragma unroll
                    for (int st = 0; st < 2; ++st) {
                        pv[st][ds] = __builtin_amdgcn_mfma_f32_16x16x32_bf16(wa[st][0], v0, pv[st][ds], 0, 0, 0);
                        pv[st][ds] = __builtin_amdgcn_mfma_f32_16x16x32_bf16(wa[st][1], v1, pv[st][ds], 0, 0, 0);
                    }
                }
            }

            bf16x8 h0, l0, h1, l1;
            unpack_pair(&u[0], h0, l0);
            unpack_pair(&u[8], h1, l1);
            const int nxt = cur ^ 1;
            *(bf16x8*)&KHL[nxt][0][sr][sd]     = h0;
            *(bf16x8*)&KHL[nxt][0][sr][sd + 8] = h1;
            *(bf16x8*)&KHL[nxt][1][sr][sd]     = l0;
            *(bf16x8*)&KHL[nxt][1][sr][sd + 8] = l1;
            __syncthreads();
            cur = nxt;
        }

        #pragma unroll
        for (int st = 0; st < 2; ++st)
            #pragma unroll
            for (int r = 0; r < 4; ++r) {
                #pragma unroll
                for (int o = 1; o <= 8; o <<= 1) z2[st][r] += __shfl_xor(z2[st][r], o, 16);
            }
    }

    // ---- epilogue: select vmean vs pv/z2; bounce; bf16 ctx plane ----
    float* Tw = (float*)&KHL[0][0][0][0] + wv * 2176;   // per-wave [32][68] f32
    #pragma unroll
    for (int st = 0; st < 2; ++st)
        #pragma unroll
        for (int r = 0; r < 4; ++r) {
            const float inv = unif[st][r] ? 0.f : (1.f / z2[st][r]);
            const int row = st * 16 + l4 * 4 + r;
            #pragma unroll
            for (int ds = 0; ds < 4; ++ds) {
                const int d = ds * 16 + l15;
                Tw[row * 68 + d] = unif[st][r] ? Vm[d] : pv[st][ds][r] * inv;
            }
        }
    asm volatile("s_waitcnt lgkmcnt(0)" ::: "memory");
    __builtin_amdgcn_sched_barrier(0);

    const int rr = lane >> 1, seg = lane & 1;
    const size_t gbase = ((size_t)b * SEQ + q0 + rr) * D_MODEL + h * D_HEAD + seg * 32;
    #pragma unroll
    for (int u2 = 0; u2 < 8; ++u2) {
        const float4 t = *(const float4*)&Tw[rr * 68 + seg * 32 + u2 * 4];
        unsigned short h4[4] = {f2bf_rne(t.x), f2bf_rne(t.y), f2bf_rne(t.z), f2bf_rne(t.w)};
        *(uint2*)&ctxh[gbase + u2 * 4] = *(const uint2*)h4;
    }
}

extern "C" void kernel_launch(void* const* d_in, const int* in_sizes, int n_in,
                              void* d_out, int out_size, void* d_ws, size_t ws_size,
                              hipStream_t stream)
{
    const float* q  = (const float*)d_in[0];
    const float* k  = (const float*)d_in[1];
    const float* v  = (const float*)d_in[2];
    const float* Wq = (const float*)d_in[3];
    const float* bq = (const float*)d_in[4];
    const float* Wk = (const float*)d_in[5];
    const float* bk = (const float*)d_in[6];
    const float* Wv = (const float*)d_in[7];
    const float* bv = (const float*)d_in[8];
    const float* Wo = (const float*)d_in[9];
    const float* bo = (const float*)d_in[10];
    float* out = (float*)d_out;

    // workspace (62 MiB), slot-reused:
    //  [0..8M)   Xh (input hi; later ctx bf16)   [8..16M)  Xl (input lo)
    //  [16..18M) Wh  [18..20M) Wlp  [20..22M) Woh
    //  [22..38M) qp (packed u32)  [38..54M) kp  [54..62M) vt
    const size_t MB = 1 << 20;
    char* w = (char*)d_ws;
    unsigned short* Xh  = (unsigned short*)(w);
    unsigned short* Xl  = (unsigned short*)(w + 8 * MB);
    unsigned short* Wh  = (unsigned short*)(w + 16 * MB);
    unsigned short* Wlp = (unsigned short*)(w + 18 * MB);
    unsigned short* Woh = (unsigned short*)(w + 20 * MB);
    unsigned* qp = (unsigned*)(w + 22 * MB);
    unsigned* kp = (unsigned*)(w + 38 * MB);
    unsigned short* vt  = (unsigned short*)(w + 54 * MB);
    unsigned short* ctxh = Xh;                    // alias: Xh dead after V-proj

    const int NA8 = (BATCH * SEQ * D_MODEL) / 8;  // 524288
    const int NW8 = (D_MODEL * D_MODEL) / 8;      // 131072
    dim3 gemmGrid(32, 8);                         // x=bm: id%8 = bm%8 (A-locality)

    conv_split2<<<(NA8 + NW8) / 256, 256, 0, stream>>>(q, Xh, Xl, NA8, Wq, Wh, Wlp, NW8);
    proj_qk<<<gemmGrid, 512, 0, stream>>>(Xh, Xl, Wh, Wlp, bq, qp, 0.125f);

    conv_split2<<<(NA8 + NW8) / 256, 256, 0, stream>>>(k, Xh, Xl, NA8, Wk, Wh, Wlp, NW8);
    proj_qk<<<gemmGrid, 512, 0, stream>>>(Xh, Xl, Wh, Wlp, bk, kp, 1.0f);

    conv_hi3<<<(NA8 + 2 * NW8) / 256, 256, 0, stream>>>(v, Xh, NA8, Wv, Wh, NW8, Wo, Woh, NW8);
    proj_vo<2><<<gemmGrid, 512, 0, stream>>>(Xh, Wh, bv, nullptr, vt, 1.0f);

    attn_mfma<<<dim3(BATCH * N_HEADS, SEQ / 128), 256, 0, stream>>>(qp, kp, vt, ctxh);

    proj_vo<0><<<gemmGrid, 512, 0, stream>>>(ctxh, Woh, bo, out, nullptr, 1.0f);
}

// Round 11
// 210.929 us; speedup vs baseline: 1.7407x; 1.6801x over previous
//
#include <hip/hip_runtime.h>
#include <math.h>

// Sparse MHA encoder: B=4, S=1024, D=1024, H=16, dk=64.
// Numerics: the 0.09 threshold is a step function on first-pass softmax.
// Score path (Q/K projections + QK^T) is split-bf16 (hi+lo, ~2^-18 rel err)
// -> E[mask flips] ~1e-4. Post-mask paths (PV, ctx, O-proj) direct bf16.
// Pass B recomputes scores BIT-IDENTICALLY to pass A (same helper, same LDS).
// Uniform-row skip: row all-masked <=> rowmax < tau = log(0.09*Z).
// R11: REVERT projections to the R4 core (256thr, 64x64/wave, in-loop
// conversion — measured 33us vs R10's "optimized" 93us; the conversion VALU
// is free latency-filler and 64x64/wave halves LDS-read per MFMA), FUSE
// Q/K/V into one dispatch (768 blocks = 2-3/CU -> cross-block overlap fills
// barrier stalls; kills converter kernels + 2 launch gaps).

constexpr int D_MODEL = 1024;
constexpr int N_HEADS = 16;
constexpr int D_HEAD  = 64;
constexpr int SEQ     = 1024;
constexpr int BATCH   = 4;
constexpr float SPARSE_THRESH = 0.09f;

typedef short  bf16x8 __attribute__((ext_vector_type(8)));
typedef float  f32x4  __attribute__((ext_vector_type(4)));

__device__ __forceinline__ unsigned short f2bf_rne(float x) {
    unsigned u = __float_as_uint(x);
    u += 0x7FFFu + ((u >> 16) & 1u);          // round-to-nearest-even
    return (unsigned short)(u >> 16);
}
__device__ __forceinline__ float bf2f(unsigned short b) {
    return __uint_as_float(((unsigned)b) << 16);
}

union BF8 { unsigned u[4]; bf16x8 v; };

// 8 packed words (hi<<16|lo) -> hi bf16x8 + lo bf16x8
__device__ __forceinline__ void unpack_pair(const unsigned* u, bf16x8& hi, bf16x8& lo) {
    BF8 h, l;
    #pragma unroll
    for (int p = 0; p < 4; ++p) {
        h.u[p] = (u[2 * p] >> 16)      | (u[2 * p + 1] & 0xFFFF0000u);
        l.u[p] = (u[2 * p] & 0xFFFFu)  | (u[2 * p + 1] << 16);
    }
    hi = h.v; lo = l.v;
}

// ============ fused Q/K/V projection (R4 core: 256 thr, 64x64/wave) ============
// z = blockIdx.z selects {Q, K, V}. C = X @ W^T + bias, split-bf16 (3 MFMA).
// z<2: packed u32 (hi<<16|lo) head-split [B,H,S,dk], scaled (Q: 1/8).
// z==2: bf16 plane TRANSPOSED [B,H,dk,S] via LDS bounce, 256B-run stores.
__global__ __launch_bounds__(256, 2)
void proj_qkv(const float* __restrict__ q, const float* __restrict__ k,
              const float* __restrict__ v,
              const float* __restrict__ Wq, const float* __restrict__ Wk,
              const float* __restrict__ Wv,
              const float* __restrict__ bq, const float* __restrict__ bk,
              const float* __restrict__ bv,
              unsigned* __restrict__ qp, unsigned* __restrict__ kp,
              unsigned short* __restrict__ vt)
{
    __shared__ unsigned short SM[4][128][40];   // A_h, A_l, B_h, B_l
    unsigned short (*A_h)[40] = SM[0];
    unsigned short (*A_l)[40] = SM[1];
    unsigned short (*B_h)[40] = SM[2];
    unsigned short (*B_l)[40] = SM[3];

    const int z = blockIdx.z;
    const float* X    = (z == 0) ? q  : (z == 1) ? k  : v;
    const float* W    = (z == 0) ? Wq : (z == 1) ? Wk : Wv;
    const float* bias = (z == 0) ? bq : (z == 1) ? bk : bv;
    const float scale = (z == 0) ? 0.125f : 1.0f;

    const int K = D_MODEL;
    const int tid = threadIdx.x, lane = tid & 63;
    const int l15 = lane & 15, l4 = lane >> 4;
    const int wv4 = tid >> 6;
    const int wr = (wv4 >> 1) * 64, wc = (wv4 & 1) * 64;
    const int bm = blockIdx.y * 128, bn = blockIdx.x * 128;
    const int sr = tid >> 1, sh = (tid & 1) * 16;

    f32x4 acc[4][4];
    #pragma unroll
    for (int i = 0; i < 4; ++i)
        #pragma unroll
        for (int j = 0; j < 4; ++j) acc[i][j] = (f32x4){0.f, 0.f, 0.f, 0.f};

    const float* ga = X + (size_t)(bm + sr) * K + sh;
    const float* gb = W + (size_t)(bn + sr) * K + sh;

    float4 av[4], bv4[4];
    #pragma unroll
    for (int l = 0; l < 4; ++l) {
        av[l]  = *(const float4*)&ga[l * 4];
        bv4[l] = *(const float4*)&gb[l * 4];
    }

    #pragma unroll 1
    for (int k0 = 0; k0 < K; k0 += 32) {
        // convert current 16+16 elems to hi/lo (VALU fills latency — R4-proven)
        unsigned short ah16[16], al16[16], bh16[16], bl16[16];
        #pragma unroll
        for (int l = 0; l < 4; ++l) {
            const float aa[4] = {av[l].x, av[l].y, av[l].z, av[l].w};
            const float bb[4] = {bv4[l].x, bv4[l].y, bv4[l].z, bv4[l].w};
            #pragma unroll
            for (int e = 0; e < 4; ++e) {
                const unsigned short h1 = f2bf_rne(aa[e]);
                ah16[l * 4 + e] = h1;
                al16[l * 4 + e] = f2bf_rne(aa[e] - bf2f(h1));
                const unsigned short h2 = f2bf_rne(bb[e]);
                bh16[l * 4 + e] = h2;
                bl16[l * 4 + e] = f2bf_rne(bb[e] - bf2f(h2));
            }
        }

        __syncthreads();                 // prior frag reads done
        #pragma unroll
        for (int g = 0; g < 2; ++g) {
            *(bf16x8*)&A_h[sr][sh + g * 8] = *(const bf16x8*)&ah16[g * 8];
            *(bf16x8*)&A_l[sr][sh + g * 8] = *(const bf16x8*)&al16[g * 8];
            *(bf16x8*)&B_h[sr][sh + g * 8] = *(const bf16x8*)&bh16[g * 8];
            *(bf16x8*)&B_l[sr][sh + g * 8] = *(const bf16x8*)&bl16[g * 8];
        }
        __syncthreads();                 // tiles ready

        if (k0 + 32 < K) {               // issue next-step loads under MFMA
            #pragma unroll
            for (int l = 0; l < 4; ++l) {
                av[l]  = *(const float4*)&ga[k0 + 32 + l * 4];
                bv4[l] = *(const float4*)&gb[k0 + 32 + l * 4];
            }
        }

        bf16x8 ah[4], al4[4], bh4[4], bl4[4];
        #pragma unroll
        for (int i = 0; i < 4; ++i) {
            const int r = wr + i * 16 + l15;
            const int c = wc + i * 16 + l15;
            ah[i]  = *(const bf16x8*)&A_h[r][l4 * 8];
            al4[i] = *(const bf16x8*)&A_l[r][l4 * 8];
            bh4[i] = *(const bf16x8*)&B_h[c][l4 * 8];
            bl4[i] = *(const bf16x8*)&B_l[c][l4 * 8];
        }
        #pragma unroll
        for (int i = 0; i < 4; ++i)
            #pragma unroll
            for (int j = 0; j < 4; ++j) {
                acc[i][j] = __builtin_amdgcn_mfma_f32_16x16x32_bf16(ah[i],  bh4[j], acc[i][j], 0, 0, 0);
                acc[i][j] = __builtin_amdgcn_mfma_f32_16x16x32_bf16(ah[i],  bl4[j], acc[i][j], 0, 0, 0);
                acc[i][j] = __builtin_amdgcn_mfma_f32_16x16x32_bf16(al4[i], bh4[j], acc[i][j], 0, 0, 0);
            }
    }

    if (z == 2) {
        // V: transpose bounce -> vt[B,H,dk,S]; 256B-run coalesced stores
        unsigned short* T = &SM[0][0][0];            // [128][136]
        __syncthreads();
        #pragma unroll
        for (int i = 0; i < 4; ++i)
            #pragma unroll
            for (int j = 0; j < 4; ++j) {
                const int cl = wc + j * 16 + l15;
                const int sl = wr + i * 16 + l4 * 4;
                const float bi = bias[bn + cl];
                unsigned short h4[4];
                #pragma unroll
                for (int r = 0; r < 4; ++r)
                    h4[r] = f2bf_rne(acc[i][j][r] + bi);
                *(uint2*)&T[cl * 136 + sl] = *(const uint2*)&h4[0];
            }
        __syncthreads();
        const int c = tid >> 1, half = tid & 1;
        const int bb = bm >> 10;
        const int sb = (bm & (SEQ - 1)) + half * 64;
        unsigned short* dst = vt + (((size_t)bb << 20) + (size_t)(bn + c) * SEQ + sb);
        const unsigned short* srcT = &T[c * 136 + half * 64];
        #pragma unroll
        for (int u = 0; u < 8; ++u)
            *(uint4*)&dst[u * 8] = *(const uint4*)&srcT[u * 8];
        return;
    }

    // Q/K: packed u32, head-split (one dword store per element — R4 cost)
    unsigned* Cp = (z == 0) ? qp : kp;
    #pragma unroll
    for (int i = 0; i < 4; ++i)
        #pragma unroll
        for (int j = 0; j < 4; ++j) {
            const int rb = bm + wr + i * 16 + l4 * 4;
            const int c  = bn + wc + j * 16 + l15;
            const float bi = bias[c];
            const int h = c >> 6, d = c & (D_HEAD - 1);
            #pragma unroll
            for (int r = 0; r < 4; ++r) {
                const float val = (acc[i][j][r] + bi) * scale;
                const unsigned short hu = f2bf_rne(val);
                const unsigned short lu = f2bf_rne(val - bf2f(hu));
                const int mrow = rb + r;
                const int b = mrow >> 10, s = mrow & (SEQ - 1);
                Cp[((size_t)(b * N_HEADS + h) * SEQ + s) * D_HEAD + d] =
                    ((unsigned)hu << 16) | lu;
            }
        }
}

// ============ O projection: bf16 ctx plane x hi(Wo), fp32 out ============
__global__ __launch_bounds__(256, 2)
void proj_o(const unsigned short* __restrict__ Act, const float* __restrict__ W,
            const float* __restrict__ bias, float* __restrict__ out)
{
    __shared__ unsigned short A_h[128][40];
    __shared__ unsigned short B_h[128][40];

    const int K = D_MODEL;
    const int tid = threadIdx.x, lane = tid & 63;
    const int l15 = lane & 15, l4 = lane >> 4;
    const int wv4 = tid >> 6;
    const int wr = (wv4 >> 1) * 64, wc = (wv4 & 1) * 64;
    const int bm = blockIdx.y * 128, bn = blockIdx.x * 128;
    const int sr = tid >> 1, sh = (tid & 1) * 16;

    f32x4 acc[4][4];
    #pragma unroll
    for (int i = 0; i < 4; ++i)
        #pragma unroll
        for (int j = 0; j < 4; ++j) acc[i][j] = (f32x4){0.f, 0.f, 0.f, 0.f};

    const unsigned short* ga = Act + (size_t)(bm + sr) * K + sh;
    const float* gb = W + (size_t)(bn + sr) * K + sh;

    uint4 av0 = *(const uint4*)&ga[0], av1 = *(const uint4*)&ga[8];
    float4 bv4[4];
    #pragma unroll
    for (int l = 0; l < 4; ++l) bv4[l] = *(const float4*)&gb[l * 4];

    #pragma unroll 1
    for (int k0 = 0; k0 < K; k0 += 32) {
        unsigned short bh16[16];
        #pragma unroll
        for (int l = 0; l < 4; ++l) {
            const float bb[4] = {bv4[l].x, bv4[l].y, bv4[l].z, bv4[l].w};
            #pragma unroll
            for (int e = 0; e < 4; ++e) bh16[l * 4 + e] = f2bf_rne(bb[e]);
        }

        __syncthreads();
        *(uint4*)&A_h[sr][sh]     = av0;
        *(uint4*)&A_h[sr][sh + 8] = av1;
        #pragma unroll
        for (int g = 0; g < 2; ++g)
            *(bf16x8*)&B_h[sr][sh + g * 8] = *(const bf16x8*)&bh16[g * 8];
        __syncthreads();

        if (k0 + 32 < K) {
            av0 = *(const uint4*)&ga[k0 + 32];
            av1 = *(const uint4*)&ga[k0 + 32 + 8];
            #pragma unroll
            for (int l = 0; l < 4; ++l)
                bv4[l] = *(const float4*)&gb[k0 + 32 + l * 4];
        }

        bf16x8 ah[4], bh4[4];
        #pragma unroll
        for (int i = 0; i < 4; ++i) {
            ah[i]  = *(const bf16x8*)&A_h[wr + i * 16 + l15][l4 * 8];
            bh4[i] = *(const bf16x8*)&B_h[wc + i * 16 + l15][l4 * 8];
        }
        #pragma unroll
        for (int i = 0; i < 4; ++i)
            #pragma unroll
            for (int j = 0; j < 4; ++j)
                acc[i][j] = __builtin_amdgcn_mfma_f32_16x16x32_bf16(ah[i], bh4[j], acc[i][j], 0, 0, 0);
    }

    #pragma unroll
    for (int i = 0; i < 4; ++i)
        #pragma unroll
        for (int j = 0; j < 4; ++j) {
            const int rb = bm + wr + i * 16 + l4 * 4;
            const int c  = bn + wc + j * 16 + l15;
            const float bi = bias[c];
            #pragma unroll
            for (int r = 0; r < 4; ++r)
                out[(size_t)(rb + r) * D_MODEL + c] = acc[i][j][r] + bi;
        }
}

// ============ MFMA attention (unchanged from R10, 67 us known) ============
__device__ __forceinline__ void score_from_lds(
    const unsigned short (* __restrict__ KH)[72], const unsigned short (* __restrict__ KL)[72],
    int l15, int l4, const bf16x8 (&qh)[2][2], const bf16x8 (&ql)[2][2], f32x4 acc[2][4])
{
    #pragma unroll
    for (int j = 0; j < 4; ++j) {
        const int row = l15 + 16 * j;
        const bf16x8 kh0 = *(const bf16x8*)&KH[row][l4 * 8];
        const bf16x8 kh1 = *(const bf16x8*)&KH[row][32 + l4 * 8];
        const bf16x8 kl0 = *(const bf16x8*)&KL[row][l4 * 8];
        const bf16x8 kl1 = *(const bf16x8*)&KL[row][32 + l4 * 8];
        #pragma unroll
        for (int st = 0; st < 2; ++st) {
            f32x4 a = (f32x4){0.f, 0.f, 0.f, 0.f};
            a = __builtin_amdgcn_mfma_f32_16x16x32_bf16(qh[st][0], kh0, a, 0, 0, 0);
            a = __builtin_amdgcn_mfma_f32_16x16x32_bf16(qh[st][0], kl0, a, 0, 0, 0);
            a = __builtin_amdgcn_mfma_f32_16x16x32_bf16(ql[st][0], kh0, a, 0, 0, 0);
            a = __builtin_amdgcn_mfma_f32_16x16x32_bf16(qh[st][1], kh1, a, 0, 0, 0);
            a = __builtin_amdgcn_mfma_f32_16x16x32_bf16(qh[st][1], kl1, a, 0, 0, 0);
            a = __builtin_amdgcn_mfma_f32_16x16x32_bf16(ql[st][1], kh1, a, 0, 0, 0);
            acc[st][j] = a;
        }
    }
}

__global__ __launch_bounds__(256, 2)
void attn_mfma(const unsigned* __restrict__ qp, const unsigned* __restrict__ kp,
               const unsigned short* __restrict__ vt, unsigned short* __restrict__ ctxh)
{
    __shared__ unsigned short KHL[2][2][64][72];
    __shared__ unsigned short Wl[4][32][72];
    __shared__ float Pm[64][4];
    __shared__ float Vm[64];
    __shared__ int AnyNU;

    const int tid  = threadIdx.x;
    const int lane = tid & 63;
    const int wv   = tid >> 6;
    const int l15  = lane & 15, l4 = lane >> 4;
    const int bh   = blockIdx.x;
    const int b    = bh >> 4, h = bh & 15;
    const int q0   = blockIdx.y * 128 + wv * 32;

    bf16x8 qh[2][2], ql[2][2];
    #pragma unroll
    for (int st = 0; st < 2; ++st) {
        const unsigned* qrow = qp + ((size_t)bh * SEQ + q0 + st * 16 + l15) * D_HEAD;
        #pragma unroll
        for (int ks = 0; ks < 2; ++ks) {
            unsigned u[8];
            *(uint4*)&u[0] = *(const uint4*)&qrow[ks * 32 + l4 * 8];
            *(uint4*)&u[4] = *(const uint4*)&qrow[ks * 32 + l4 * 8 + 4];
            unpack_pair(u, qh[st][ks], ql[st][ks]);
        }
    }

    const unsigned short* vtb = vt + (size_t)bh * D_HEAD * SEQ;

    {
        const int d = tid >> 2, q4 = tid & 3;
        const unsigned short* vr = vtb + (size_t)d * SEQ + q4 * 256;
        float s0 = 0.f, s1 = 0.f, s2 = 0.f, s3 = 0.f;
        #pragma unroll 4
        for (int i = 0; i < 32; ++i) {
            bf16x8 v8 = *(const bf16x8*)&vr[i * 8];
            s0 += bf2f((unsigned short)v8[0]) + bf2f((unsigned short)v8[4]);
            s1 += bf2f((unsigned short)v8[1]) + bf2f((unsigned short)v8[5]);
            s2 += bf2f((unsigned short)v8[2]) + bf2f((unsigned short)v8[6]);
            s3 += bf2f((unsigned short)v8[3]) + bf2f((unsigned short)v8[7]);
        }
        Pm[d][q4] = (s0 + s1) + (s2 + s3);
        if (tid == 0) AnyNU = 0;
    }

    const int sr = tid >> 2;
    const int sd = (tid & 3) * 16;
    const unsigned* kpb = kp + (size_t)bh * SEQ * D_HEAD;

    {
        unsigned u[16];
        const unsigned* src = kpb + (size_t)sr * D_HEAD + sd;
        #pragma unroll
        for (int g = 0; g < 4; ++g) *(uint4*)&u[g * 4] = *(const uint4*)&src[g * 4];
        bf16x8 h0, l0, h1, l1;
        unpack_pair(&u[0], h0, l0);
        unpack_pair(&u[8], h1, l1);
        *(bf16x8*)&KHL[0][0][sr][sd]     = h0;
        *(bf16x8*)&KHL[0][0][sr][sd + 8] = h1;
        *(bf16x8*)&KHL[0][1][sr][sd]     = l0;
        *(bf16x8*)&KHL[0][1][sr][sd + 8] = l1;
    }
    __syncthreads();

    if (tid < 64)
        Vm[tid] = (Pm[tid][0] + Pm[tid][1] + Pm[tid][2] + Pm[tid][3]) * (1.f / 1024.f);

    float mloc[2][4], zloc[2][4];
    #pragma unroll
    for (int st = 0; st < 2; ++st)
        #pragma unroll
        for (int r = 0; r < 4; ++r) { mloc[st][r] = -1e30f; zloc[st][r] = 0.f; }

    int cur = 0;

    #pragma unroll 1
    for (int c = 0; c < 16; ++c) {
        unsigned u[16];
        const int cn = (c + 1) & 15;
        const unsigned* src = kpb + ((size_t)cn * 64 + sr) * D_HEAD + sd;
        #pragma unroll
        for (int g = 0; g < 4; ++g) *(uint4*)&u[g * 4] = *(const uint4*)&src[g * 4];

        f32x4 acc[2][4];
        score_from_lds(KHL[cur][0], KHL[cur][1], l15, l4, qh, ql, acc);

        #pragma unroll
        for (int st = 0; st < 2; ++st)
            #pragma unroll
            for (int r = 0; r < 4; ++r) {
                const float a0 = acc[st][0][r], a1 = acc[st][1][r];
                const float a2 = acc[st][2][r], a3 = acc[st][3][r];
                mloc[st][r] = fmaxf(mloc[st][r], fmaxf(fmaxf(a0, a1), fmaxf(a2, a3)));
                zloc[st][r] += (__expf(a0) + __expf(a1)) + (__expf(a2) + __expf(a3));
            }

        bf16x8 h0, l0, h1, l1;
        unpack_pair(&u[0], h0, l0);
        unpack_pair(&u[8], h1, l1);
        const int nxt = cur ^ 1;
        *(bf16x8*)&KHL[nxt][0][sr][sd]     = h0;
        *(bf16x8*)&KHL[nxt][0][sr][sd + 8] = h1;
        *(bf16x8*)&KHL[nxt][1][sr][sd]     = l0;
        *(bf16x8*)&KHL[nxt][1][sr][sd + 8] = l1;
        __syncthreads();
        cur = nxt;
    }

    float taue[2][4];
    bool  unif[2][4];
    int mynu = 0;
    #pragma unroll
    for (int st = 0; st < 2; ++st)
        #pragma unroll
        for (int r = 0; r < 4; ++r) {
            float mm = mloc[st][r], zz = zloc[st][r];
            #pragma unroll
            for (int o = 1; o <= 8; o <<= 1) {
                mm = fmaxf(mm, __shfl_xor(mm, o, 16));
                zz += __shfl_xor(zz, o, 16);
            }
            const float tau = __logf(SPARSE_THRESH * zz);
            const bool uni = (mm < tau);
            unif[st][r] = uni;
            taue[st][r] = uni ? 3.0e38f : tau;
            mynu |= uni ? 0 : 1;
        }
    if (__any(mynu)) { if (lane == 0) atomicOr(&AnyNU, 1); }
    __syncthreads();
    const bool runB = (AnyNU != 0);

    float z2[2][4];
    f32x4 pv[2][4];
    #pragma unroll
    for (int st = 0; st < 2; ++st)
        #pragma unroll
        for (int r = 0; r < 4; ++r) { z2[st][r] = 0.f; pv[st][r] = (f32x4){0.f, 0.f, 0.f, 0.f}; }

    if (runB) {
        #pragma unroll 1
        for (int c = 0; c < 16; ++c) {
            unsigned u[16];
            const int cn = (c + 1) & 15;
            const unsigned* src = kpb + ((size_t)cn * 64 + sr) * D_HEAD + sd;
            #pragma unroll
            for (int g = 0; g < 4; ++g) *(uint4*)&u[g * 4] = *(const uint4*)&src[g * 4];

            f32x4 acc[2][4];
            score_from_lds(KHL[cur][0], KHL[cur][1], l15, l4, qh, ql, acc);

            int any = 0;
            #pragma unroll
            for (int st = 0; st < 2; ++st)
                #pragma unroll
                for (int r = 0; r < 4; ++r) {
                    const float rmax = fmaxf(fmaxf(acc[st][0][r], acc[st][1][r]),
                                             fmaxf(acc[st][2][r], acc[st][3][r]));
                    any |= (rmax >= taue[st][r]) ? 1 : 0;
                }

            if (__any(any)) {
                #pragma unroll
                for (int st = 0; st < 2; ++st)
                    #pragma unroll
                    for (int j = 0; j < 4; ++j)
                        #pragma unroll
                        for (int r = 0; r < 4; ++r) {
                            const float a = acc[st][j][r];
                            const float w = (a >= taue[st][r]) ? __expf(a) : 0.f;
                            const unsigned short wb = f2bf_rne(w);
                            z2[st][r] += bf2f(wb);
                            Wl[wv][st * 16 + l4 * 4 + r][l15 + 16 * j] = wb;
                        }
                asm volatile("s_waitcnt lgkmcnt(0)" ::: "memory");
                __builtin_amdgcn_sched_barrier(0);

                bf16x8 wa[2][2];
                #pragma unroll
                for (int st = 0; st < 2; ++st)
                    #pragma unroll
                    for (int ks = 0; ks < 2; ++ks)
                        wa[st][ks] = *(const bf16x8*)&Wl[wv][st * 16 + l15][ks * 32 + l4 * 8];

                #pragma unroll
                for (int ds = 0; ds < 4; ++ds) {
                    const bf16x8 v0 = *(const bf16x8*)
                        &vtb[(size_t)(ds * 16 + l15) * SEQ + c * 64 + l4 * 8];
                    const bf16x8 v1 = *(const bf16x8*)
                        &vtb[(size_t)(ds * 16 + l15) * SEQ + c * 64 + 32 + l4 * 8];
                    #pragma unroll
                    for (int st = 0; st < 2; ++st) {
                        pv[st][ds] = __builtin_amdgcn_mfma_f32_16x16x32_bf16(wa[st][0], v0, pv[st][ds], 0, 0, 0);
                        pv[st][ds] = __builtin_amdgcn_mfma_f32_16x16x32_bf16(wa[st][1], v1, pv[st][ds], 0, 0, 0);
                    }
                }
            }

            bf16x8 h0, l0, h1, l1;
            unpack_pair(&u[0], h0, l0);
            unpack_pair(&u[8], h1, l1);
            const int nxt = cur ^ 1;
            *(bf16x8*)&KHL[nxt][0][sr][sd]     = h0;
            *(bf16x8*)&KHL[nxt][0][sr][sd + 8] = h1;
            *(bf16x8*)&KHL[nxt][1][sr][sd]     = l0;
            *(bf16x8*)&KHL[nxt][1][sr][sd + 8] = l1;
            __syncthreads();
            cur = nxt;
        }

        #pragma unroll
        for (int st = 0; st < 2; ++st)
            #pragma unroll
            for (int r = 0; r < 4; ++r) {
                #pragma unroll
                for (int o = 1; o <= 8; o <<= 1) z2[st][r] += __shfl_xor(z2[st][r], o, 16);
            }
    }

    float* Tw = (float*)&KHL[0][0][0][0] + wv * 2176;
    #pragma unroll
    for (int st = 0; st < 2; ++st)
        #pragma unroll
        for (int r = 0; r < 4; ++r) {
            const float inv = unif[st][r] ? 0.f : (1.f / z2[st][r]);
            const int row = st * 16 + l4 * 4 + r;
            #pragma unroll
            for (int ds = 0; ds < 4; ++ds) {
                const int d = ds * 16 + l15;
                Tw[row * 68 + d] = unif[st][r] ? Vm[d] : pv[st][ds][r] * inv;
            }
        }
    asm volatile("s_waitcnt lgkmcnt(0)" ::: "memory");
    __builtin_amdgcn_sched_barrier(0);

    const int rr = lane >> 1, seg = lane & 1;
    const size_t gbase = ((size_t)b * SEQ + q0 + rr) * D_MODEL + h * D_HEAD + seg * 32;
    #pragma unroll
    for (int u2 = 0; u2 < 8; ++u2) {
        const float4 t = *(const float4*)&Tw[rr * 68 + seg * 32 + u2 * 4];
        unsigned short h4[4] = {f2bf_rne(t.x), f2bf_rne(t.y), f2bf_rne(t.z), f2bf_rne(t.w)};
        *(uint2*)&ctxh[gbase + u2 * 4] = *(const uint2*)h4;
    }
}

extern "C" void kernel_launch(void* const* d_in, const int* in_sizes, int n_in,
                              void* d_out, int out_size, void* d_ws, size_t ws_size,
                              hipStream_t stream)
{
    const float* q  = (const float*)d_in[0];
    const float* k  = (const float*)d_in[1];
    const float* v  = (const float*)d_in[2];
    const float* Wq = (const float*)d_in[3];
    const float* bq = (const float*)d_in[4];
    const float* Wk = (const float*)d_in[5];
    const float* bk = (const float*)d_in[6];
    const float* Wv = (const float*)d_in[7];
    const float* bv = (const float*)d_in[8];
    const float* Wo = (const float*)d_in[9];
    const float* bo = (const float*)d_in[10];
    float* out = (float*)d_out;

    // workspace (48 MiB): qp 16 + kp 16 + vt 8 + ctxh 8
    const size_t MB = 1 << 20;
    char* w = (char*)d_ws;
    unsigned* qp = (unsigned*)(w);
    unsigned* kp = (unsigned*)(w + 16 * MB);
    unsigned short* vt   = (unsigned short*)(w + 32 * MB);
    unsigned short* ctxh = (unsigned short*)(w + 40 * MB);

    // fused Q/K/V: 768 blocks (2-3 resident/CU -> cross-block latency hiding)
    proj_qkv<<<dim3(8, 32, 3), 256, 0, stream>>>(q, k, v, Wq, Wk, Wv,
                                                 bq, bk, bv, qp, kp, vt);

    // bh on x: all 8 q-blocks of a (b,h) share an XCD (id%8 = bh%8)
    attn_mfma<<<dim3(BATCH * N_HEADS, SEQ / 128), 256, 0, stream>>>(qp, kp, vt, ctxh);

    proj_o<<<dim3(8, 32), 256, 0, stream>>>(ctxh, Wo, bo, out);
}

// Round 12
// 184.819 us; speedup vs baseline: 1.9866x; 1.1413x over previous
//
#include <hip/hip_runtime.h>
#include <math.h>

// Sparse MHA encoder: B=4, S=1024, D=1024, H=16, dk=64.
// Numerics: the 0.09 threshold is a step function on first-pass softmax.
// Score path (Q/K projections + QK^T) is split-bf16 (hi+lo, ~2^-18 rel err)
// -> E[mask flips] ~1e-4. Post-mask paths (PV, ctx, O-proj) direct bf16.
// Pass B recomputes scores BIT-IDENTICALLY to pass A (same helper, same LDS).
// Uniform-row skip: row all-masked <=> rowmax < tau = log(0.09*Z).
// R12: scheduling-only changes on R11 (outputs bit-identical):
//  (a) grid (32,8,3): id%8 = bm%8 -> the 8 bn-blocks sharing an A-tile-row
//      co-reside on one XCD (R11 FETCH 203MB = 3.4x A re-fetch across XCDs);
//  (b) __launch_bounds__(256,3): all 3 blocks/CU resident (768 blocks total)
//      -> cross-block stall-filling, no serialized tail (R11 occupancy 17.5%
//      showed the 2-block cap left 1/3 of the dispatch as a tail).

constexpr int D_MODEL = 1024;
constexpr int N_HEADS = 16;
constexpr int D_HEAD  = 64;
constexpr int SEQ     = 1024;
constexpr int BATCH   = 4;
constexpr float SPARSE_THRESH = 0.09f;

typedef short  bf16x8 __attribute__((ext_vector_type(8)));
typedef float  f32x4  __attribute__((ext_vector_type(4)));

__device__ __forceinline__ unsigned short f2bf_rne(float x) {
    unsigned u = __float_as_uint(x);
    u += 0x7FFFu + ((u >> 16) & 1u);          // round-to-nearest-even
    return (unsigned short)(u >> 16);
}
__device__ __forceinline__ float bf2f(unsigned short b) {
    return __uint_as_float(((unsigned)b) << 16);
}

union BF8 { unsigned u[4]; bf16x8 v; };

// 8 packed words (hi<<16|lo) -> hi bf16x8 + lo bf16x8
__device__ __forceinline__ void unpack_pair(const unsigned* u, bf16x8& hi, bf16x8& lo) {
    BF8 h, l;
    #pragma unroll
    for (int p = 0; p < 4; ++p) {
        h.u[p] = (u[2 * p] >> 16)      | (u[2 * p + 1] & 0xFFFF0000u);
        l.u[p] = (u[2 * p] & 0xFFFFu)  | (u[2 * p + 1] << 16);
    }
    hi = h.v; lo = l.v;
}

// ============ fused Q/K/V projection (R4 core: 256 thr, 64x64/wave) ============
// z = blockIdx.z selects {Q, K, V}. C = X @ W^T + bias, split-bf16 (3 MFMA).
// z<2: packed u32 (hi<<16|lo) head-split [B,H,S,dk], scaled (Q: 1/8).
// z==2: bf16 plane TRANSPOSED [B,H,dk,S] via LDS bounce, 256B-run stores.
// Grid (32,8,3): x=bm -> id%8 = bm%8 (A-row XCD locality).
__global__ __launch_bounds__(256, 3)
void proj_qkv(const float* __restrict__ q, const float* __restrict__ k,
              const float* __restrict__ v,
              const float* __restrict__ Wq, const float* __restrict__ Wk,
              const float* __restrict__ Wv,
              const float* __restrict__ bq, const float* __restrict__ bk,
              const float* __restrict__ bv,
              unsigned* __restrict__ qp, unsigned* __restrict__ kp,
              unsigned short* __restrict__ vt)
{
    __shared__ unsigned short SM[4][128][40];   // A_h, A_l, B_h, B_l
    unsigned short (*A_h)[40] = SM[0];
    unsigned short (*A_l)[40] = SM[1];
    unsigned short (*B_h)[40] = SM[2];
    unsigned short (*B_l)[40] = SM[3];

    const int z = blockIdx.z;
    const float* X    = (z == 0) ? q  : (z == 1) ? k  : v;
    const float* W    = (z == 0) ? Wq : (z == 1) ? Wk : Wv;
    const float* bias = (z == 0) ? bq : (z == 1) ? bk : bv;
    const float scale = (z == 0) ? 0.125f : 1.0f;

    const int K = D_MODEL;
    const int tid = threadIdx.x, lane = tid & 63;
    const int l15 = lane & 15, l4 = lane >> 4;
    const int wv4 = tid >> 6;
    const int wr = (wv4 >> 1) * 64, wc = (wv4 & 1) * 64;
    const int bm = blockIdx.x * 128, bn = blockIdx.y * 128;   // x=bm (XCD locality)
    const int sr = tid >> 1, sh = (tid & 1) * 16;

    f32x4 acc[4][4];
    #pragma unroll
    for (int i = 0; i < 4; ++i)
        #pragma unroll
        for (int j = 0; j < 4; ++j) acc[i][j] = (f32x4){0.f, 0.f, 0.f, 0.f};

    const float* ga = X + (size_t)(bm + sr) * K + sh;
    const float* gb = W + (size_t)(bn + sr) * K + sh;

    float4 av[4], bv4[4];
    #pragma unroll
    for (int l = 0; l < 4; ++l) {
        av[l]  = *(const float4*)&ga[l * 4];
        bv4[l] = *(const float4*)&gb[l * 4];
    }

    #pragma unroll 1
    for (int k0 = 0; k0 < K; k0 += 32) {
        // convert current 16+16 elems to hi/lo (VALU fills latency — R4-proven)
        unsigned short ah16[16], al16[16], bh16[16], bl16[16];
        #pragma unroll
        for (int l = 0; l < 4; ++l) {
            const float aa[4] = {av[l].x, av[l].y, av[l].z, av[l].w};
            const float bb[4] = {bv4[l].x, bv4[l].y, bv4[l].z, bv4[l].w};
            #pragma unroll
            for (int e = 0; e < 4; ++e) {
                const unsigned short h1 = f2bf_rne(aa[e]);
                ah16[l * 4 + e] = h1;
                al16[l * 4 + e] = f2bf_rne(aa[e] - bf2f(h1));
                const unsigned short h2 = f2bf_rne(bb[e]);
                bh16[l * 4 + e] = h2;
                bl16[l * 4 + e] = f2bf_rne(bb[e] - bf2f(h2));
            }
        }

        __syncthreads();                 // prior frag reads done
        #pragma unroll
        for (int g = 0; g < 2; ++g) {
            *(bf16x8*)&A_h[sr][sh + g * 8] = *(const bf16x8*)&ah16[g * 8];
            *(bf16x8*)&A_l[sr][sh + g * 8] = *(const bf16x8*)&al16[g * 8];
            *(bf16x8*)&B_h[sr][sh + g * 8] = *(const bf16x8*)&bh16[g * 8];
            *(bf16x8*)&B_l[sr][sh + g * 8] = *(const bf16x8*)&bl16[g * 8];
        }
        __syncthreads();                 // tiles ready

        if (k0 + 32 < K) {               // issue next-step loads under MFMA
            #pragma unroll
            for (int l = 0; l < 4; ++l) {
                av[l]  = *(const float4*)&ga[k0 + 32 + l * 4];
                bv4[l] = *(const float4*)&gb[k0 + 32 + l * 4];
            }
        }

        bf16x8 ah[4], al4[4], bh4[4], bl4[4];
        #pragma unroll
        for (int i = 0; i < 4; ++i) {
            const int r = wr + i * 16 + l15;
            const int c = wc + i * 16 + l15;
            ah[i]  = *(const bf16x8*)&A_h[r][l4 * 8];
            al4[i] = *(const bf16x8*)&A_l[r][l4 * 8];
            bh4[i] = *(const bf16x8*)&B_h[c][l4 * 8];
            bl4[i] = *(const bf16x8*)&B_l[c][l4 * 8];
        }
        #pragma unroll
        for (int i = 0; i < 4; ++i)
            #pragma unroll
            for (int j = 0; j < 4; ++j) {
                acc[i][j] = __builtin_amdgcn_mfma_f32_16x16x32_bf16(ah[i],  bh4[j], acc[i][j], 0, 0, 0);
                acc[i][j] = __builtin_amdgcn_mfma_f32_16x16x32_bf16(ah[i],  bl4[j], acc[i][j], 0, 0, 0);
                acc[i][j] = __builtin_amdgcn_mfma_f32_16x16x32_bf16(al4[i], bh4[j], acc[i][j], 0, 0, 0);
            }
    }

    if (z == 2) {
        // V: transpose bounce -> vt[B,H,dk,S]; 256B-run coalesced stores
        unsigned short* T = &SM[0][0][0];            // [128][136]
        __syncthreads();
        #pragma unroll
        for (int i = 0; i < 4; ++i)
            #pragma unroll
            for (int j = 0; j < 4; ++j) {
                const int cl = wc + j * 16 + l15;
                const int sl = wr + i * 16 + l4 * 4;
                const float bi = bias[bn + cl];
                unsigned short h4[4];
                #pragma unroll
                for (int r = 0; r < 4; ++r)
                    h4[r] = f2bf_rne(acc[i][j][r] + bi);
                *(uint2*)&T[cl * 136 + sl] = *(const uint2*)&h4[0];
            }
        __syncthreads();
        const int c = tid >> 1, half = tid & 1;
        const int bb = bm >> 10;
        const int sb = (bm & (SEQ - 1)) + half * 64;
        unsigned short* dst = vt + (((size_t)bb << 20) + (size_t)(bn + c) * SEQ + sb);
        const unsigned short* srcT = &T[c * 136 + half * 64];
        #pragma unroll
        for (int u = 0; u < 8; ++u)
            *(uint4*)&dst[u * 8] = *(const uint4*)&srcT[u * 8];
        return;
    }

    // Q/K: packed u32, head-split (one dword store per element — R4 cost)
    unsigned* Cp = (z == 0) ? qp : kp;
    #pragma unroll
    for (int i = 0; i < 4; ++i)
        #pragma unroll
        for (int j = 0; j < 4; ++j) {
            const int rb = bm + wr + i * 16 + l4 * 4;
            const int c  = bn + wc + j * 16 + l15;
            const float bi = bias[c];
            const int h = c >> 6, d = c & (D_HEAD - 1);
            #pragma unroll
            for (int r = 0; r < 4; ++r) {
                const float val = (acc[i][j][r] + bi) * scale;
                const unsigned short hu = f2bf_rne(val);
                const unsigned short lu = f2bf_rne(val - bf2f(hu));
                const int mrow = rb + r;
                const int b = mrow >> 10, s = mrow & (SEQ - 1);
                Cp[((size_t)(b * N_HEADS + h) * SEQ + s) * D_HEAD + d] =
                    ((unsigned)hu << 16) | lu;
            }
        }
}

// ============ O projection: bf16 ctx plane x hi(Wo), fp32 out ============
// Grid (32,8): x=bm (A = ctx plane, same XCD-locality argument).
__global__ __launch_bounds__(256, 3)
void proj_o(const unsigned short* __restrict__ Act, const float* __restrict__ W,
            const float* __restrict__ bias, float* __restrict__ out)
{
    __shared__ unsigned short A_h[128][40];
    __shared__ unsigned short B_h[128][40];

    const int K = D_MODEL;
    const int tid = threadIdx.x, lane = tid & 63;
    const int l15 = lane & 15, l4 = lane >> 4;
    const int wv4 = tid >> 6;
    const int wr = (wv4 >> 1) * 64, wc = (wv4 & 1) * 64;
    const int bm = blockIdx.x * 128, bn = blockIdx.y * 128;
    const int sr = tid >> 1, sh = (tid & 1) * 16;

    f32x4 acc[4][4];
    #pragma unroll
    for (int i = 0; i < 4; ++i)
        #pragma unroll
        for (int j = 0; j < 4; ++j) acc[i][j] = (f32x4){0.f, 0.f, 0.f, 0.f};

    const unsigned short* ga = Act + (size_t)(bm + sr) * K + sh;
    const float* gb = W + (size_t)(bn + sr) * K + sh;

    uint4 av0 = *(const uint4*)&ga[0], av1 = *(const uint4*)&ga[8];
    float4 bv4[4];
    #pragma unroll
    for (int l = 0; l < 4; ++l) bv4[l] = *(const float4*)&gb[l * 4];

    #pragma unroll 1
    for (int k0 = 0; k0 < K; k0 += 32) {
        unsigned short bh16[16];
        #pragma unroll
        for (int l = 0; l < 4; ++l) {
            const float bb[4] = {bv4[l].x, bv4[l].y, bv4[l].z, bv4[l].w};
            #pragma unroll
            for (int e = 0; e < 4; ++e) bh16[l * 4 + e] = f2bf_rne(bb[e]);
        }

        __syncthreads();
        *(uint4*)&A_h[sr][sh]     = av0;
        *(uint4*)&A_h[sr][sh + 8] = av1;
        #pragma unroll
        for (int g = 0; g < 2; ++g)
            *(bf16x8*)&B_h[sr][sh + g * 8] = *(const bf16x8*)&bh16[g * 8];
        __syncthreads();

        if (k0 + 32 < K) {
            av0 = *(const uint4*)&ga[k0 + 32];
            av1 = *(const uint4*)&ga[k0 + 32 + 8];
            #pragma unroll
            for (int l = 0; l < 4; ++l)
                bv4[l] = *(const float4*)&gb[k0 + 32 + l * 4];
        }

        bf16x8 ah[4], bh4[4];
        #pragma unroll
        for (int i = 0; i < 4; ++i) {
            ah[i]  = *(const bf16x8*)&A_h[wr + i * 16 + l15][l4 * 8];
            bh4[i] = *(const bf16x8*)&B_h[wc + i * 16 + l15][l4 * 8];
        }
        #pragma unroll
        for (int i = 0; i < 4; ++i)
            #pragma unroll
            for (int j = 0; j < 4; ++j)
                acc[i][j] = __builtin_amdgcn_mfma_f32_16x16x32_bf16(ah[i], bh4[j], acc[i][j], 0, 0, 0);
    }

    #pragma unroll
    for (int i = 0; i < 4; ++i)
        #pragma unroll
        for (int j = 0; j < 4; ++j) {
            const int rb = bm + wr + i * 16 + l4 * 4;
            const int c  = bn + wc + j * 16 + l15;
            const float bi = bias[c];
            #pragma unroll
            for (int r = 0; r < 4; ++r)
                out[(size_t)(rb + r) * D_MODEL + c] = acc[i][j][r] + bi;
        }
}

// ============ MFMA attention (unchanged) ============
__device__ __forceinline__ void score_from_lds(
    const unsigned short (* __restrict__ KH)[72], const unsigned short (* __restrict__ KL)[72],
    int l15, int l4, const bf16x8 (&qh)[2][2], const bf16x8 (&ql)[2][2], f32x4 acc[2][4])
{
    #pragma unroll
    for (int j = 0; j < 4; ++j) {
        const int row = l15 + 16 * j;
        const bf16x8 kh0 = *(const bf16x8*)&KH[row][l4 * 8];
        const bf16x8 kh1 = *(const bf16x8*)&KH[row][32 + l4 * 8];
        const bf16x8 kl0 = *(const bf16x8*)&KL[row][l4 * 8];
        const bf16x8 kl1 = *(const bf16x8*)&KL[row][32 + l4 * 8];
        #pragma unroll
        for (int st = 0; st < 2; ++st) {
            f32x4 a = (f32x4){0.f, 0.f, 0.f, 0.f};
            a = __builtin_amdgcn_mfma_f32_16x16x32_bf16(qh[st][0], kh0, a, 0, 0, 0);
            a = __builtin_amdgcn_mfma_f32_16x16x32_bf16(qh[st][0], kl0, a, 0, 0, 0);
            a = __builtin_amdgcn_mfma_f32_16x16x32_bf16(ql[st][0], kh0, a, 0, 0, 0);
            a = __builtin_amdgcn_mfma_f32_16x16x32_bf16(qh[st][1], kh1, a, 0, 0, 0);
            a = __builtin_amdgcn_mfma_f32_16x16x32_bf16(qh[st][1], kl1, a, 0, 0, 0);
            a = __builtin_amdgcn_mfma_f32_16x16x32_bf16(ql[st][1], kh1, a, 0, 0, 0);
            acc[st][j] = a;
        }
    }
}

__global__ __launch_bounds__(256, 2)
void attn_mfma(const unsigned* __restrict__ qp, const unsigned* __restrict__ kp,
               const unsigned short* __restrict__ vt, unsigned short* __restrict__ ctxh)
{
    __shared__ unsigned short KHL[2][2][64][72];
    __shared__ unsigned short Wl[4][32][72];
    __shared__ float Pm[64][4];
    __shared__ float Vm[64];
    __shared__ int AnyNU;

    const int tid  = threadIdx.x;
    const int lane = tid & 63;
    const int wv   = tid >> 6;
    const int l15  = lane & 15, l4 = lane >> 4;
    const int bh   = blockIdx.x;
    const int b    = bh >> 4, h = bh & 15;
    const int q0   = blockIdx.y * 128 + wv * 32;

    bf16x8 qh[2][2], ql[2][2];
    #pragma unroll
    for (int st = 0; st < 2; ++st) {
        const unsigned* qrow = qp + ((size_t)bh * SEQ + q0 + st * 16 + l15) * D_HEAD;
        #pragma unroll
        for (int ks = 0; ks < 2; ++ks) {
            unsigned u[8];
            *(uint4*)&u[0] = *(const uint4*)&qrow[ks * 32 + l4 * 8];
            *(uint4*)&u[4] = *(const uint4*)&qrow[ks * 32 + l4 * 8 + 4];
            unpack_pair(u, qh[st][ks], ql[st][ks]);
        }
    }

    const unsigned short* vtb = vt + (size_t)bh * D_HEAD * SEQ;

    {
        const int d = tid >> 2, q4 = tid & 3;
        const unsigned short* vr = vtb + (size_t)d * SEQ + q4 * 256;
        float s0 = 0.f, s1 = 0.f, s2 = 0.f, s3 = 0.f;
        #pragma unroll 4
        for (int i = 0; i < 32; ++i) {
            bf16x8 v8 = *(const bf16x8*)&vr[i * 8];
            s0 += bf2f((unsigned short)v8[0]) + bf2f((unsigned short)v8[4]);
            s1 += bf2f((unsigned short)v8[1]) + bf2f((unsigned short)v8[5]);
            s2 += bf2f((unsigned short)v8[2]) + bf2f((unsigned short)v8[6]);
            s3 += bf2f((unsigned short)v8[3]) + bf2f((unsigned short)v8[7]);
        }
        Pm[d][q4] = (s0 + s1) + (s2 + s3);
        if (tid == 0) AnyNU = 0;
    }

    const int sr = tid >> 2;
    const int sd = (tid & 3) * 16;
    const unsigned* kpb = kp + (size_t)bh * SEQ * D_HEAD;

    {
        unsigned u[16];
        const unsigned* src = kpb + (size_t)sr * D_HEAD + sd;
        #pragma unroll
        for (int g = 0; g < 4; ++g) *(uint4*)&u[g * 4] = *(const uint4*)&src[g * 4];
        bf16x8 h0, l0, h1, l1;
        unpack_pair(&u[0], h0, l0);
        unpack_pair(&u[8], h1, l1);
        *(bf16x8*)&KHL[0][0][sr][sd]     = h0;
        *(bf16x8*)&KHL[0][0][sr][sd + 8] = h1;
        *(bf16x8*)&KHL[0][1][sr][sd]     = l0;
        *(bf16x8*)&KHL[0][1][sr][sd + 8] = l1;
    }
    __syncthreads();

    if (tid < 64)
        Vm[tid] = (Pm[tid][0] + Pm[tid][1] + Pm[tid][2] + Pm[tid][3]) * (1.f / 1024.f);

    float mloc[2][4], zloc[2][4];
    #pragma unroll
    for (int st = 0; st < 2; ++st)
        #pragma unroll
        for (int r = 0; r < 4; ++r) { mloc[st][r] = -1e30f; zloc[st][r] = 0.f; }

    int cur = 0;

    #pragma unroll 1
    for (int c = 0; c < 16; ++c) {
        unsigned u[16];
        const int cn = (c + 1) & 15;
        const unsigned* src = kpb + ((size_t)cn * 64 + sr) * D_HEAD + sd;
        #pragma unroll
        for (int g = 0; g < 4; ++g) *(uint4*)&u[g * 4] = *(const uint4*)&src[g * 4];

        f32x4 acc[2][4];
        score_from_lds(KHL[cur][0], KHL[cur][1], l15, l4, qh, ql, acc);

        #pragma unroll
        for (int st = 0; st < 2; ++st)
            #pragma unroll
            for (int r = 0; r < 4; ++r) {
                const float a0 = acc[st][0][r], a1 = acc[st][1][r];
                const float a2 = acc[st][2][r], a3 = acc[st][3][r];
                mloc[st][r] = fmaxf(mloc[st][r], fmaxf(fmaxf(a0, a1), fmaxf(a2, a3)));
                zloc[st][r] += (__expf(a0) + __expf(a1)) + (__expf(a2) + __expf(a3));
            }

        bf16x8 h0, l0, h1, l1;
        unpack_pair(&u[0], h0, l0);
        unpack_pair(&u[8], h1, l1);
        const int nxt = cur ^ 1;
        *(bf16x8*)&KHL[nxt][0][sr][sd]     = h0;
        *(bf16x8*)&KHL[nxt][0][sr][sd + 8] = h1;
        *(bf16x8*)&KHL[nxt][1][sr][sd]     = l0;
        *(bf16x8*)&KHL[nxt][1][sr][sd + 8] = l1;
        __syncthreads();
        cur = nxt;
    }

    float taue[2][4];
    bool  unif[2][4];
    int mynu = 0;
    #pragma unroll
    for (int st = 0; st < 2; ++st)
        #pragma unroll
        for (int r = 0; r < 4; ++r) {
            float mm = mloc[st][r], zz = zloc[st][r];
            #pragma unroll
            for (int o = 1; o <= 8; o <<= 1) {
                mm = fmaxf(mm, __shfl_xor(mm, o, 16));
                zz += __shfl_xor(zz, o, 16);
            }
            const float tau = __logf(SPARSE_THRESH * zz);
            const bool uni = (mm < tau);
            unif[st][r] = uni;
            taue[st][r] = uni ? 3.0e38f : tau;
            mynu |= uni ? 0 : 1;
        }
    if (__any(mynu)) { if (lane == 0) atomicOr(&AnyNU, 1); }
    __syncthreads();
    const bool runB = (AnyNU != 0);

    float z2[2][4];
    f32x4 pv[2][4];
    #pragma unroll
    for (int st = 0; st < 2; ++st)
        #pragma unroll
        for (int r = 0; r < 4; ++r) { z2[st][r] = 0.f; pv[st][r] = (f32x4){0.f, 0.f, 0.f, 0.f}; }

    if (runB) {
        #pragma unroll 1
        for (int c = 0; c < 16; ++c) {
            unsigned u[16];
            const int cn = (c + 1) & 15;
            const unsigned* src = kpb + ((size_t)cn * 64 + sr) * D_HEAD + sd;
            #pragma unroll
            for (int g = 0; g < 4; ++g) *(uint4*)&u[g * 4] = *(const uint4*)&src[g * 4];

            f32x4 acc[2][4];
            score_from_lds(KHL[cur][0], KHL[cur][1], l15, l4, qh, ql, acc);

            int any = 0;
            #pragma unroll
            for (int st = 0; st < 2; ++st)
                #pragma unroll
                for (int r = 0; r < 4; ++r) {
                    const float rmax = fmaxf(fmaxf(acc[st][0][r], acc[st][1][r]),
                                             fmaxf(acc[st][2][r], acc[st][3][r]));
                    any |= (rmax >= taue[st][r]) ? 1 : 0;
                }

            if (__any(any)) {
                #pragma unroll
                for (int st = 0; st < 2; ++st)
                    #pragma unroll
                    for (int j = 0; j < 4; ++j)
                        #pragma unroll
                        for (int r = 0; r < 4; ++r) {
                            const float a = acc[st][j][r];
                            const float w = (a >= taue[st][r]) ? __expf(a) : 0.f;
                            const unsigned short wb = f2bf_rne(w);
                            z2[st][r] += bf2f(wb);
                            Wl[wv][st * 16 + l4 * 4 + r][l15 + 16 * j] = wb;
                        }
                asm volatile("s_waitcnt lgkmcnt(0)" ::: "memory");
                __builtin_amdgcn_sched_barrier(0);

                bf16x8 wa[2][2];
                #pragma unroll
                for (int st = 0; st < 2; ++st)
                    #pragma unroll
                    for (int ks = 0; ks < 2; ++ks)
                        wa[st][ks] = *(const bf16x8*)&Wl[wv][st * 16 + l15][ks * 32 + l4 * 8];

                #pragma unroll
                for (int ds = 0; ds < 4; ++ds) {
                    const bf16x8 v0 = *(const bf16x8*)
                        &vtb[(size_t)(ds * 16 + l15) * SEQ + c * 64 + l4 * 8];
                    const bf16x8 v1 = *(const bf16x8*)
                        &vtb[(size_t)(ds * 16 + l15) * SEQ + c * 64 + 32 + l4 * 8];
                    #pragma unroll
                    for (int st = 0; st < 2; ++st) {
                        pv[st][ds] = __builtin_amdgcn_mfma_f32_16x16x32_bf16(wa[st][0], v0, pv[st][ds], 0, 0, 0);
                        pv[st][ds] = __builtin_amdgcn_mfma_f32_16x16x32_bf16(wa[st][1], v1, pv[st][ds], 0, 0, 0);
                    }
                }
            }

            bf16x8 h0, l0, h1, l1;
            unpack_pair(&u[0], h0, l0);
            unpack_pair(&u[8], h1, l1);
            const int nxt = cur ^ 1;
            *(bf16x8*)&KHL[nxt][0][sr][sd]     = h0;
            *(bf16x8*)&KHL[nxt][0][sr][sd + 8] = h1;
            *(bf16x8*)&KHL[nxt][1][sr][sd]     = l0;
            *(bf16x8*)&KHL[nxt][1][sr][sd + 8] = l1;
            __syncthreads();
            cur = nxt;
        }

        #pragma unroll
        for (int st = 0; st < 2; ++st)
            #pragma unroll
            for (int r = 0; r < 4; ++r) {
                #pragma unroll
                for (int o = 1; o <= 8; o <<= 1) z2[st][r] += __shfl_xor(z2[st][r], o, 16);
            }
    }

    float* Tw = (float*)&KHL[0][0][0][0] + wv * 2176;
    #pragma unroll
    for (int st = 0; st < 2; ++st)
        #pragma unroll
        for (int r = 0; r < 4; ++r) {
            const float inv = unif[st][r] ? 0.f : (1.f / z2[st][r]);
            const int row = st * 16 + l4 * 4 + r;
            #pragma unroll
            for (int ds = 0; ds < 4; ++ds) {
                const int d = ds * 16 + l15;
                Tw[row * 68 + d] = unif[st][r] ? Vm[d] : pv[st][ds][r] * inv;
            }
        }
    asm volatile("s_waitcnt lgkmcnt(0)" ::: "memory");
    __builtin_amdgcn_sched_barrier(0);

    const int rr = lane >> 1, seg = lane & 1;
    const size_t gbase = ((size_t)b * SEQ + q0 + rr) * D_MODEL + h * D_HEAD + seg * 32;
    #pragma unroll
    for (int u2 = 0; u2 < 8; ++u2) {
        const float4 t = *(const float4*)&Tw[rr * 68 + seg * 32 + u2 * 4];
        unsigned short h4[4] = {f2bf_rne(t.x), f2bf_rne(t.y), f2bf_rne(t.z), f2bf_rne(t.w)};
        *(uint2*)&ctxh[gbase + u2 * 4] = *(const uint2*)h4;
    }
}

extern "C" void kernel_launch(void* const* d_in, const int* in_sizes, int n_in,
                              void* d_out, int out_size, void* d_ws, size_t ws_size,
                              hipStream_t stream)
{
    const float* q  = (const float*)d_in[0];
    const float* k  = (const float*)d_in[1];
    const float* v  = (const float*)d_in[2];
    const float* Wq = (const float*)d_in[3];
    const float* bq = (const float*)d_in[4];
    const float* Wk = (const float*)d_in[5];
    const float* bk = (const float*)d_in[6];
    const float* Wv = (const float*)d_in[7];
    const float* bv = (const float*)d_in[8];
    const float* Wo = (const float*)d_in[9];
    const float* bo = (const float*)d_in[10];
    float* out = (float*)d_out;

    // workspace (48 MiB): qp 16 + kp 16 + vt 8 + ctxh 8
    const size_t MB = 1 << 20;
    char* w = (char*)d_ws;
    unsigned* qp = (unsigned*)(w);
    unsigned* kp = (unsigned*)(w + 16 * MB);
    unsigned short* vt   = (unsigned short*)(w + 32 * MB);
    unsigned short* ctxh = (unsigned short*)(w + 40 * MB);

    // fused Q/K/V: grid (32,8,3), x=bm -> id%8 = bm%8 (A-row XCD locality);
    // 3 blocks/CU all resident (launch_bounds(256,3))
    proj_qkv<<<dim3(32, 8, 3), 256, 0, stream>>>(q, k, v, Wq, Wk, Wv,
                                                 bq, bk, bv, qp, kp, vt);

    // bh on x: all 8 q-blocks of a (b,h) share an XCD (id%8 = bh%8)
    attn_mfma<<<dim3(BATCH * N_HEADS, SEQ / 128), 256, 0, stream>>>(qp, kp, vt, ctxh);

    proj_o<<<dim3(32, 8), 256, 0, stream>>>(ctxh, Wo, bo, out);
}

// Round 13
// 179.546 us; speedup vs baseline: 2.0450x; 1.0294x over previous
//
#include <hip/hip_runtime.h>
#include <hip/hip_bf16.h>
#include <math.h>

// Sparse MHA encoder: B=4, S=1024, D=1024, H=16, dk=64.
// Numerics: the 0.09 threshold is a step function on first-pass softmax.
// Score path (Q/K projections + QK^T) is split-bf16 (hi+lo, ~2^-18 rel err)
// -> E[mask flips] ~1e-4. Post-mask paths (PV, ctx, O-proj) direct bf16.
// Pass B recomputes scores BIT-IDENTICALLY to pass A (same helper, same LDS).
// Uniform-row skip: row all-masked <=> rowmax < tau = log(0.09*Z).
// R13: proj_qkv was conversion-VALU-bound (R12: VALUBusy 43% vs MfmaUtil 29%).
//  (a) W conversion hoisted to tiny conv_w kernel (weights were re-converted
//      32x across bm-blocks); A conversion STAYS in-loop (R9 lesson: it is
//      productive latency filler).
//  (b) A conversion via v_cvt_pk_bf16_f32 (__float22bfloat162_rn, RNE ==
//      f2bf_rne on normal inputs -> outputs bit-identical); residuals by
//      masking the packed word. ~3 VALU/value vs 10.

constexpr int D_MODEL = 1024;
constexpr int N_HEADS = 16;
constexpr int D_HEAD  = 64;
constexpr int SEQ     = 1024;
constexpr int BATCH   = 4;
constexpr float SPARSE_THRESH = 0.09f;

typedef short  bf16x8 __attribute__((ext_vector_type(8)));
typedef float  f32x4  __attribute__((ext_vector_type(4)));

__device__ __forceinline__ unsigned short f2bf_rne(float x) {
    unsigned u = __float_as_uint(x);
    u += 0x7FFFu + ((u >> 16) & 1u);          // round-to-nearest-even
    return (unsigned short)(u >> 16);
}
__device__ __forceinline__ float bf2f(unsigned short b) {
    return __uint_as_float(((unsigned)b) << 16);
}

// packed RNE pair-convert: low16 = bf16(a), high16 = bf16(b)  (v_cvt_pk_bf16_f32)
__device__ __forceinline__ unsigned cvt2(float a, float b) {
    __hip_bfloat162 p = __float22bfloat162_rn(make_float2(a, b));
    unsigned u; __builtin_memcpy(&u, &p, 4); return u;
}
// split 4 floats -> 2 packed hi words + 2 packed lo words
__device__ __forceinline__ void split4(float x0, float x1, float x2, float x3,
                                       unsigned* hw, unsigned* lw) {
    const unsigned uh0 = cvt2(x0, x1);
    hw[0] = uh0;
    lw[0] = cvt2(x0 - __uint_as_float(uh0 << 16),
                 x1 - __uint_as_float(uh0 & 0xFFFF0000u));
    const unsigned uh1 = cvt2(x2, x3);
    hw[1] = uh1;
    lw[1] = cvt2(x2 - __uint_as_float(uh1 << 16),
                 x3 - __uint_as_float(uh1 & 0xFFFF0000u));
}

union BF8 { unsigned u[4]; bf16x8 v; };

// 8 packed words (hi<<16|lo) -> hi bf16x8 + lo bf16x8
__device__ __forceinline__ void unpack_pair(const unsigned* u, bf16x8& hi, bf16x8& lo) {
    BF8 h, l;
    #pragma unroll
    for (int p = 0; p < 4; ++p) {
        h.u[p] = (u[2 * p] >> 16)      | (u[2 * p + 1] & 0xFFFF0000u);
        l.u[p] = (u[2 * p] & 0xFFFFu)  | (u[2 * p + 1] << 16);
    }
    hi = h.v; lo = l.v;
}

// ============ weight pre-split: Wq/Wk/Wv -> hi/lo bf16 planes ============
__global__ __launch_bounds__(256)
void conv_w(const float* __restrict__ Wq, const float* __restrict__ Wk,
            const float* __restrict__ Wv,
            unsigned short* __restrict__ Wqh, unsigned short* __restrict__ Wql,
            unsigned short* __restrict__ Wkh, unsigned short* __restrict__ Wkl,
            unsigned short* __restrict__ Wvh, unsigned short* __restrict__ Wvl)
{
    const int NW8 = (D_MODEL * D_MODEL) / 8;      // 131072
    int i = blockIdx.x * 256 + threadIdx.x;
    const float* s; unsigned short *dh, *dl;
    if (i < NW8)            { s = Wq; dh = Wqh; dl = Wql; }
    else if (i < 2 * NW8)   { i -= NW8; s = Wk; dh = Wkh; dl = Wkl; }
    else                    { i -= 2 * NW8; s = Wv; dh = Wvh; dl = Wvl; }
    const float4 x0 = ((const float4*)(s + (size_t)i * 8))[0];
    const float4 x1 = ((const float4*)(s + (size_t)i * 8))[1];
    unsigned hw[4], lw[4];
    split4(x0.x, x0.y, x0.z, x0.w, &hw[0], &lw[0]);
    split4(x1.x, x1.y, x1.z, x1.w, &hw[2], &lw[2]);
    *(uint4*)&dh[(size_t)i * 8] = *(const uint4*)hw;
    *(uint4*)&dl[(size_t)i * 8] = *(const uint4*)lw;
}

// ============ fused Q/K/V projection (256 thr, 64x64/wave) ============
// z selects {Q,K,V}. A (input) split in-loop via cvt_pk; W pre-split planes.
// z<2: packed u32 (hi<<16|lo) head-split [B,H,S,dk], scaled (Q: 1/8).
// z==2: bf16 plane TRANSPOSED [B,H,dk,S] via LDS bounce, 256B-run stores.
// Grid (32,8,3): x=bm -> id%8 = bm%8 (A-row XCD locality).
__global__ __launch_bounds__(256, 3)
void proj_qkv(const float* __restrict__ q, const float* __restrict__ k,
              const float* __restrict__ v,
              const unsigned short* __restrict__ Wqh, const unsigned short* __restrict__ Wql,
              const unsigned short* __restrict__ Wkh, const unsigned short* __restrict__ Wkl,
              const unsigned short* __restrict__ Wvh, const unsigned short* __restrict__ Wvl,
              const float* __restrict__ bq, const float* __restrict__ bk,
              const float* __restrict__ bv,
              unsigned* __restrict__ qp, unsigned* __restrict__ kp,
              unsigned short* __restrict__ vt)
{
    __shared__ unsigned short SM[4][128][40];   // A_h, A_l, B_h, B_l
    unsigned short (*A_h)[40] = SM[0];
    unsigned short (*A_l)[40] = SM[1];
    unsigned short (*B_h)[40] = SM[2];
    unsigned short (*B_l)[40] = SM[3];

    const int z = blockIdx.z;
    const float* X    = (z == 0) ? q   : (z == 1) ? k   : v;
    const unsigned short* Wh = (z == 0) ? Wqh : (z == 1) ? Wkh : Wvh;
    const unsigned short* Wl = (z == 0) ? Wql : (z == 1) ? Wkl : Wvl;
    const float* bias = (z == 0) ? bq  : (z == 1) ? bk  : bv;
    const float scale = (z == 0) ? 0.125f : 1.0f;

    const int K = D_MODEL;
    const int tid = threadIdx.x, lane = tid & 63;
    const int l15 = lane & 15, l4 = lane >> 4;
    const int wv4 = tid >> 6;
    const int wr = (wv4 >> 1) * 64, wc = (wv4 & 1) * 64;
    const int bm = blockIdx.x * 128, bn = blockIdx.y * 128;   // x=bm (XCD locality)
    const int sr = tid >> 1, sh = (tid & 1) * 16;

    f32x4 acc[4][4];
    #pragma unroll
    for (int i = 0; i < 4; ++i)
        #pragma unroll
        for (int j = 0; j < 4; ++j) acc[i][j] = (f32x4){0.f, 0.f, 0.f, 0.f};

    const float* ga = X + (size_t)(bm + sr) * K + sh;
    const unsigned short* gbh = Wh + (size_t)(bn + sr) * K + sh;
    const unsigned short* gbl = Wl + (size_t)(bn + sr) * K + sh;

    float4 av[4];
    uint4 wbh0, wbh1, wbl0, wbl1;
    #pragma unroll
    for (int l = 0; l < 4; ++l) av[l] = *(const float4*)&ga[l * 4];
    wbh0 = *(const uint4*)&gbh[0]; wbh1 = *(const uint4*)&gbh[8];
    wbl0 = *(const uint4*)&gbl[0]; wbl1 = *(const uint4*)&gbl[8];

    #pragma unroll 1
    for (int k0 = 0; k0 < K; k0 += 32) {
        // split A (cvt_pk path: ~3 VALU/value; productive latency filler)
        unsigned ahw[8], alw[8];
        #pragma unroll
        for (int l = 0; l < 4; ++l)
            split4(av[l].x, av[l].y, av[l].z, av[l].w, &ahw[l * 2], &alw[l * 2]);

        __syncthreads();                 // prior frag reads done
        *(uint4*)&A_h[sr][sh]     = *(const uint4*)&ahw[0];
        *(uint4*)&A_h[sr][sh + 8] = *(const uint4*)&ahw[4];
        *(uint4*)&A_l[sr][sh]     = *(const uint4*)&alw[0];
        *(uint4*)&A_l[sr][sh + 8] = *(const uint4*)&alw[4];
        *(uint4*)&B_h[sr][sh]     = wbh0;
        *(uint4*)&B_h[sr][sh + 8] = wbh1;
        *(uint4*)&B_l[sr][sh]     = wbl0;
        *(uint4*)&B_l[sr][sh + 8] = wbl1;
        __syncthreads();                 // tiles ready

        if (k0 + 32 < K) {               // issue next-step loads under MFMA
            const int o = k0 + 32;
            #pragma unroll
            for (int l = 0; l < 4; ++l) av[l] = *(const float4*)&ga[o + l * 4];
            wbh0 = *(const uint4*)&gbh[o]; wbh1 = *(const uint4*)&gbh[o + 8];
            wbl0 = *(const uint4*)&gbl[o]; wbl1 = *(const uint4*)&gbl[o + 8];
        }

        bf16x8 ah[4], al4[4], bh4[4], bl4[4];
        #pragma unroll
        for (int i = 0; i < 4; ++i) {
            const int r = wr + i * 16 + l15;
            const int c = wc + i * 16 + l15;
            ah[i]  = *(const bf16x8*)&A_h[r][l4 * 8];
            al4[i] = *(const bf16x8*)&A_l[r][l4 * 8];
            bh4[i] = *(const bf16x8*)&B_h[c][l4 * 8];
            bl4[i] = *(const bf16x8*)&B_l[c][l4 * 8];
        }
        #pragma unroll
        for (int i = 0; i < 4; ++i)
            #pragma unroll
            for (int j = 0; j < 4; ++j) {
                acc[i][j] = __builtin_amdgcn_mfma_f32_16x16x32_bf16(ah[i],  bh4[j], acc[i][j], 0, 0, 0);
                acc[i][j] = __builtin_amdgcn_mfma_f32_16x16x32_bf16(ah[i],  bl4[j], acc[i][j], 0, 0, 0);
                acc[i][j] = __builtin_amdgcn_mfma_f32_16x16x32_bf16(al4[i], bh4[j], acc[i][j], 0, 0, 0);
            }
    }

    if (z == 2) {
        // V: transpose bounce -> vt[B,H,dk,S]; 256B-run coalesced stores
        unsigned short* T = &SM[0][0][0];            // [128][136]
        __syncthreads();
        #pragma unroll
        for (int i = 0; i < 4; ++i)
            #pragma unroll
            for (int j = 0; j < 4; ++j) {
                const int cl = wc + j * 16 + l15;
                const int sl = wr + i * 16 + l4 * 4;
                const float bi = bias[bn + cl];
                unsigned short h4[4];
                #pragma unroll
                for (int r = 0; r < 4; ++r)
                    h4[r] = f2bf_rne(acc[i][j][r] + bi);
                *(uint2*)&T[cl * 136 + sl] = *(const uint2*)&h4[0];
            }
        __syncthreads();
        const int c = tid >> 1, half = tid & 1;
        const int bb = bm >> 10;
        const int sb = (bm & (SEQ - 1)) + half * 64;
        unsigned short* dst = vt + (((size_t)bb << 20) + (size_t)(bn + c) * SEQ + sb);
        const unsigned short* srcT = &T[c * 136 + half * 64];
        #pragma unroll
        for (int u = 0; u < 8; ++u)
            *(uint4*)&dst[u * 8] = *(const uint4*)&srcT[u * 8];
        return;
    }

    // Q/K: packed u32, head-split
    unsigned* Cp = (z == 0) ? qp : kp;
    #pragma unroll
    for (int i = 0; i < 4; ++i)
        #pragma unroll
        for (int j = 0; j < 4; ++j) {
            const int rb = bm + wr + i * 16 + l4 * 4;
            const int c  = bn + wc + j * 16 + l15;
            const float bi = bias[c];
            const int h = c >> 6, d = c & (D_HEAD - 1);
            #pragma unroll
            for (int r = 0; r < 4; ++r) {
                const float val = (acc[i][j][r] + bi) * scale;
                const unsigned short hu = f2bf_rne(val);
                const unsigned short lu = f2bf_rne(val - bf2f(hu));
                const int mrow = rb + r;
                const int b = mrow >> 10, s = mrow & (SEQ - 1);
                Cp[((size_t)(b * N_HEADS + h) * SEQ + s) * D_HEAD + d] =
                    ((unsigned)hu << 16) | lu;
            }
        }
}

// ============ O projection: bf16 ctx plane x hi(Wo), fp32 out ============
__global__ __launch_bounds__(256, 3)
void proj_o(const unsigned short* __restrict__ Act, const float* __restrict__ W,
            const float* __restrict__ bias, float* __restrict__ out)
{
    __shared__ unsigned short A_h[128][40];
    __shared__ unsigned short B_h[128][40];

    const int K = D_MODEL;
    const int tid = threadIdx.x, lane = tid & 63;
    const int l15 = lane & 15, l4 = lane >> 4;
    const int wv4 = tid >> 6;
    const int wr = (wv4 >> 1) * 64, wc = (wv4 & 1) * 64;
    const int bm = blockIdx.x * 128, bn = blockIdx.y * 128;
    const int sr = tid >> 1, sh = (tid & 1) * 16;

    f32x4 acc[4][4];
    #pragma unroll
    for (int i = 0; i < 4; ++i)
        #pragma unroll
        for (int j = 0; j < 4; ++j) acc[i][j] = (f32x4){0.f, 0.f, 0.f, 0.f};

    const unsigned short* ga = Act + (size_t)(bm + sr) * K + sh;
    const float* gb = W + (size_t)(bn + sr) * K + sh;

    uint4 av0 = *(const uint4*)&ga[0], av1 = *(const uint4*)&ga[8];
    float4 bv4[4];
    #pragma unroll
    for (int l = 0; l < 4; ++l) bv4[l] = *(const float4*)&gb[l * 4];

    #pragma unroll 1
    for (int k0 = 0; k0 < K; k0 += 32) {
        unsigned bhw[8];
        #pragma unroll
        for (int l = 0; l < 4; ++l) {
            bhw[l * 2]     = cvt2(bv4[l].x, bv4[l].y);
            bhw[l * 2 + 1] = cvt2(bv4[l].z, bv4[l].w);
        }

        __syncthreads();
        *(uint4*)&A_h[sr][sh]     = av0;
        *(uint4*)&A_h[sr][sh + 8] = av1;
        *(uint4*)&B_h[sr][sh]     = *(const uint4*)&bhw[0];
        *(uint4*)&B_h[sr][sh + 8] = *(const uint4*)&bhw[4];
        __syncthreads();

        if (k0 + 32 < K) {
            av0 = *(const uint4*)&ga[k0 + 32];
            av1 = *(const uint4*)&ga[k0 + 32 + 8];
            #pragma unroll
            for (int l = 0; l < 4; ++l)
                bv4[l] = *(const float4*)&gb[k0 + 32 + l * 4];
        }

        bf16x8 ah[4], bh4[4];
        #pragma unroll
        for (int i = 0; i < 4; ++i) {
            ah[i]  = *(const bf16x8*)&A_h[wr + i * 16 + l15][l4 * 8];
            bh4[i] = *(const bf16x8*)&B_h[wc + i * 16 + l15][l4 * 8];
        }
        #pragma unroll
        for (int i = 0; i < 4; ++i)
            #pragma unroll
            for (int j = 0; j < 4; ++j)
                acc[i][j] = __builtin_amdgcn_mfma_f32_16x16x32_bf16(ah[i], bh4[j], acc[i][j], 0, 0, 0);
    }

    #pragma unroll
    for (int i = 0; i < 4; ++i)
        #pragma unroll
        for (int j = 0; j < 4; ++j) {
            const int rb = bm + wr + i * 16 + l4 * 4;
            const int c  = bn + wc + j * 16 + l15;
            const float bi = bias[c];
            #pragma unroll
            for (int r = 0; r < 4; ++r)
                out[(size_t)(rb + r) * D_MODEL + c] = acc[i][j][r] + bi;
        }
}

// ============ MFMA attention (unchanged) ============
__device__ __forceinline__ void score_from_lds(
    const unsigned short (* __restrict__ KH)[72], const unsigned short (* __restrict__ KL)[72],
    int l15, int l4, const bf16x8 (&qh)[2][2], const bf16x8 (&ql)[2][2], f32x4 acc[2][4])
{
    #pragma unroll
    for (int j = 0; j < 4; ++j) {
        const int row = l15 + 16 * j;
        const bf16x8 kh0 = *(const bf16x8*)&KH[row][l4 * 8];
        const bf16x8 kh1 = *(const bf16x8*)&KH[row][32 + l4 * 8];
        const bf16x8 kl0 = *(const bf16x8*)&KL[row][l4 * 8];
        const bf16x8 kl1 = *(const bf16x8*)&KL[row][32 + l4 * 8];
        #pragma unroll
        for (int st = 0; st < 2; ++st) {
            f32x4 a = (f32x4){0.f, 0.f, 0.f, 0.f};
            a = __builtin_amdgcn_mfma_f32_16x16x32_bf16(qh[st][0], kh0, a, 0, 0, 0);
            a = __builtin_amdgcn_mfma_f32_16x16x32_bf16(qh[st][0], kl0, a, 0, 0, 0);
            a = __builtin_amdgcn_mfma_f32_16x16x32_bf16(ql[st][0], kh0, a, 0, 0, 0);
            a = __builtin_amdgcn_mfma_f32_16x16x32_bf16(qh[st][1], kh1, a, 0, 0, 0);
            a = __builtin_amdgcn_mfma_f32_16x16x32_bf16(qh[st][1], kl1, a, 0, 0, 0);
            a = __builtin_amdgcn_mfma_f32_16x16x32_bf16(ql[st][1], kh1, a, 0, 0, 0);
            acc[st][j] = a;
        }
    }
}

__global__ __launch_bounds__(256, 2)
void attn_mfma(const unsigned* __restrict__ qp, const unsigned* __restrict__ kp,
               const unsigned short* __restrict__ vt, unsigned short* __restrict__ ctxh)
{
    __shared__ unsigned short KHL[2][2][64][72];
    __shared__ unsigned short Wl[4][32][72];
    __shared__ float Pm[64][4];
    __shared__ float Vm[64];
    __shared__ int AnyNU;

    const int tid  = threadIdx.x;
    const int lane = tid & 63;
    const int wv   = tid >> 6;
    const int l15  = lane & 15, l4 = lane >> 4;
    const int bh   = blockIdx.x;
    const int b    = bh >> 4, h = bh & 15;
    const int q0   = blockIdx.y * 128 + wv * 32;

    bf16x8 qh[2][2], ql[2][2];
    #pragma unroll
    for (int st = 0; st < 2; ++st) {
        const unsigned* qrow = qp + ((size_t)bh * SEQ + q0 + st * 16 + l15) * D_HEAD;
        #pragma unroll
        for (int ks = 0; ks < 2; ++ks) {
            unsigned u[8];
            *(uint4*)&u[0] = *(const uint4*)&qrow[ks * 32 + l4 * 8];
            *(uint4*)&u[4] = *(const uint4*)&qrow[ks * 32 + l4 * 8 + 4];
            unpack_pair(u, qh[st][ks], ql[st][ks]);
        }
    }

    const unsigned short* vtb = vt + (size_t)bh * D_HEAD * SEQ;

    {
        const int d = tid >> 2, q4 = tid & 3;
        const unsigned short* vr = vtb + (size_t)d * SEQ + q4 * 256;
        float s0 = 0.f, s1 = 0.f, s2 = 0.f, s3 = 0.f;
        #pragma unroll 4
        for (int i = 0; i < 32; ++i) {
            bf16x8 v8 = *(const bf16x8*)&vr[i * 8];
            s0 += bf2f((unsigned short)v8[0]) + bf2f((unsigned short)v8[4]);
            s1 += bf2f((unsigned short)v8[1]) + bf2f((unsigned short)v8[5]);
            s2 += bf2f((unsigned short)v8[2]) + bf2f((unsigned short)v8[6]);
            s3 += bf2f((unsigned short)v8[3]) + bf2f((unsigned short)v8[7]);
        }
        Pm[d][q4] = (s0 + s1) + (s2 + s3);
        if (tid == 0) AnyNU = 0;
    }

    const int sr = tid >> 2;
    const int sd = (tid & 3) * 16;
    const unsigned* kpb = kp + (size_t)bh * SEQ * D_HEAD;

    {
        unsigned u[16];
        const unsigned* src = kpb + (size_t)sr * D_HEAD + sd;
        #pragma unroll
        for (int g = 0; g < 4; ++g) *(uint4*)&u[g * 4] = *(const uint4*)&src[g * 4];
        bf16x8 h0, l0, h1, l1;
        unpack_pair(&u[0], h0, l0);
        unpack_pair(&u[8], h1, l1);
        *(bf16x8*)&KHL[0][0][sr][sd]     = h0;
        *(bf16x8*)&KHL[0][0][sr][sd + 8] = h1;
        *(bf16x8*)&KHL[0][1][sr][sd]     = l0;
        *(bf16x8*)&KHL[0][1][sr][sd + 8] = l1;
    }
    __syncthreads();

    if (tid < 64)
        Vm[tid] = (Pm[tid][0] + Pm[tid][1] + Pm[tid][2] + Pm[tid][3]) * (1.f / 1024.f);

    float mloc[2][4], zloc[2][4];
    #pragma unroll
    for (int st = 0; st < 2; ++st)
        #pragma unroll
        for (int r = 0; r < 4; ++r) { mloc[st][r] = -1e30f; zloc[st][r] = 0.f; }

    int cur = 0;

    #pragma unroll 1
    for (int c = 0; c < 16; ++c) {
        unsigned u[16];
        const int cn = (c + 1) & 15;
        const unsigned* src = kpb + ((size_t)cn * 64 + sr) * D_HEAD + sd;
        #pragma unroll
        for (int g = 0; g < 4; ++g) *(uint4*)&u[g * 4] = *(const uint4*)&src[g * 4];

        f32x4 acc[2][4];
        score_from_lds(KHL[cur][0], KHL[cur][1], l15, l4, qh, ql, acc);

        #pragma unroll
        for (int st = 0; st < 2; ++st)
            #pragma unroll
            for (int r = 0; r < 4; ++r) {
                const float a0 = acc[st][0][r], a1 = acc[st][1][r];
                const float a2 = acc[st][2][r], a3 = acc[st][3][r];
                mloc[st][r] = fmaxf(mloc[st][r], fmaxf(fmaxf(a0, a1), fmaxf(a2, a3)));
                zloc[st][r] += (__expf(a0) + __expf(a1)) + (__expf(a2) + __expf(a3));
            }

        bf16x8 h0, l0, h1, l1;
        unpack_pair(&u[0], h0, l0);
        unpack_pair(&u[8], h1, l1);
        const int nxt = cur ^ 1;
        *(bf16x8*)&KHL[nxt][0][sr][sd]     = h0;
        *(bf16x8*)&KHL[nxt][0][sr][sd + 8] = h1;
        *(bf16x8*)&KHL[nxt][1][sr][sd]     = l0;
        *(bf16x8*)&KHL[nxt][1][sr][sd + 8] = l1;
        __syncthreads();
        cur = nxt;
    }

    float taue[2][4];
    bool  unif[2][4];
    int mynu = 0;
    #pragma unroll
    for (int st = 0; st < 2; ++st)
        #pragma unroll
        for (int r = 0; r < 4; ++r) {
            float mm = mloc[st][r], zz = zloc[st][r];
            #pragma unroll
            for (int o = 1; o <= 8; o <<= 1) {
                mm = fmaxf(mm, __shfl_xor(mm, o, 16));
                zz += __shfl_xor(zz, o, 16);
            }
            const float tau = __logf(SPARSE_THRESH * zz);
            const bool uni = (mm < tau);
            unif[st][r] = uni;
            taue[st][r] = uni ? 3.0e38f : tau;
            mynu |= uni ? 0 : 1;
        }
    if (__any(mynu)) { if (lane == 0) atomicOr(&AnyNU, 1); }
    __syncthreads();
    const bool runB = (AnyNU != 0);

    float z2[2][4];
    f32x4 pv[2][4];
    #pragma unroll
    for (int st = 0; st < 2; ++st)
        #pragma unroll
        for (int r = 0; r < 4; ++r) { z2[st][r] = 0.f; pv[st][r] = (f32x4){0.f, 0.f, 0.f, 0.f}; }

    if (runB) {
        #pragma unroll 1
        for (int c = 0; c < 16; ++c) {
            unsigned u[16];
            const int cn = (c + 1) & 15;
            const unsigned* src = kpb + ((size_t)cn * 64 + sr) * D_HEAD + sd;
            #pragma unroll
            for (int g = 0; g < 4; ++g) *(uint4*)&u[g * 4] = *(const uint4*)&src[g * 4];

            f32x4 acc[2][4];
            score_from_lds(KHL[cur][0], KHL[cur][1], l15, l4, qh, ql, acc);

            int any = 0;
            #pragma unroll
            for (int st = 0; st < 2; ++st)
                #pragma unroll
                for (int r = 0; r < 4; ++r) {
                    const float rmax = fmaxf(fmaxf(acc[st][0][r], acc[st][1][r]),
                                             fmaxf(acc[st][2][r], acc[st][3][r]));
                    any |= (rmax >= taue[st][r]) ? 1 : 0;
                }

            if (__any(any)) {
                #pragma unroll
                for (int st = 0; st < 2; ++st)
                    #pragma unroll
                    for (int j = 0; j < 4; ++j)
                        #pragma unroll
                        for (int r = 0; r < 4; ++r) {
                            const float a = acc[st][j][r];
                            const float w = (a >= taue[st][r]) ? __expf(a) : 0.f;
                            const unsigned short wb = f2bf_rne(w);
                            z2[st][r] += bf2f(wb);
                            Wl[wv][st * 16 + l4 * 4 + r][l15 + 16 * j] = wb;
                        }
                asm volatile("s_waitcnt lgkmcnt(0)" ::: "memory");
                __builtin_amdgcn_sched_barrier(0);

                bf16x8 wa[2][2];
                #pragma unroll
                for (int st = 0; st < 2; ++st)
                    #pragma unroll
                    for (int ks = 0; ks < 2; ++ks)
                        wa[st][ks] = *(const bf16x8*)&Wl[wv][st * 16 + l15][ks * 32 + l4 * 8];

                #pragma unroll
                for (int ds = 0; ds < 4; ++ds) {
                    const bf16x8 v0 = *(const bf16x8*)
                        &vtb[(size_t)(ds * 16 + l15) * SEQ + c * 64 + l4 * 8];
                    const bf16x8 v1 = *(const bf16x8*)
                        &vtb[(size_t)(ds * 16 + l15) * SEQ + c * 64 + 32 + l4 * 8];
                    #pragma unroll
                    for (int st = 0; st < 2; ++st) {
                        pv[st][ds] = __builtin_amdgcn_mfma_f32_16x16x32_bf16(wa[st][0], v0, pv[st][ds], 0, 0, 0);
                        pv[st][ds] = __builtin_amdgcn_mfma_f32_16x16x32_bf16(wa[st][1], v1, pv[st][ds], 0, 0, 0);
                    }
                }
            }

            bf16x8 h0, l0, h1, l1;
            unpack_pair(&u[0], h0, l0);
            unpack_pair(&u[8], h1, l1);
            const int nxt = cur ^ 1;
            *(bf16x8*)&KHL[nxt][0][sr][sd]     = h0;
            *(bf16x8*)&KHL[nxt][0][sr][sd + 8] = h1;
            *(bf16x8*)&KHL[nxt][1][sr][sd]     = l0;
            *(bf16x8*)&KHL[nxt][1][sr][sd + 8] = l1;
            __syncthreads();
            cur = nxt;
        }

        #pragma unroll
        for (int st = 0; st < 2; ++st)
            #pragma unroll
            for (int r = 0; r < 4; ++r) {
                #pragma unroll
                for (int o = 1; o <= 8; o <<= 1) z2[st][r] += __shfl_xor(z2[st][r], o, 16);
            }
    }

    float* Tw = (float*)&KHL[0][0][0][0] + wv * 2176;
    #pragma unroll
    for (int st = 0; st < 2; ++st)
        #pragma unroll
        for (int r = 0; r < 4; ++r) {
            const float inv = unif[st][r] ? 0.f : (1.f / z2[st][r]);
            const int row = st * 16 + l4 * 4 + r;
            #pragma unroll
            for (int ds = 0; ds < 4; ++ds) {
                const int d = ds * 16 + l15;
                Tw[row * 68 + d] = unif[st][r] ? Vm[d] : pv[st][ds][r] * inv;
            }
        }
    asm volatile("s_waitcnt lgkmcnt(0)" ::: "memory");
    __builtin_amdgcn_sched_barrier(0);

    const int rr = lane >> 1, seg = lane & 1;
    const size_t gbase = ((size_t)b * SEQ + q0 + rr) * D_MODEL + h * D_HEAD + seg * 32;
    #pragma unroll
    for (int u2 = 0; u2 < 8; ++u2) {
        const float4 t = *(const float4*)&Tw[rr * 68 + seg * 32 + u2 * 4];
        unsigned short h4[4] = {f2bf_rne(t.x), f2bf_rne(t.y), f2bf_rne(t.z), f2bf_rne(t.w)};
        *(uint2*)&ctxh[gbase + u2 * 4] = *(const uint2*)h4;
    }
}

extern "C" void kernel_launch(void* const* d_in, const int* in_sizes, int n_in,
                              void* d_out, int out_size, void* d_ws, size_t ws_size,
                              hipStream_t stream)
{
    const float* q  = (const float*)d_in[0];
    const float* k  = (const float*)d_in[1];
    const float* v  = (const float*)d_in[2];
    const float* Wq = (const float*)d_in[3];
    const float* bq = (const float*)d_in[4];
    const float* Wk = (const float*)d_in[5];
    const float* bk = (const float*)d_in[6];
    const float* Wv = (const float*)d_in[7];
    const float* bv = (const float*)d_in[8];
    const float* Wo = (const float*)d_in[9];
    const float* bo = (const float*)d_in[10];
    float* out = (float*)d_out;

    // workspace (60 MiB): qp 16 + kp 16 + vt 8 + ctxh 8 + 6 weight planes (12)
    const size_t MB = 1 << 20;
    char* w = (char*)d_ws;
    unsigned* qp = (unsigned*)(w);
    unsigned* kp = (unsigned*)(w + 16 * MB);
    unsigned short* vt   = (unsigned short*)(w + 32 * MB);
    unsigned short* ctxh = (unsigned short*)(w + 40 * MB);
    unsigned short* Wqh = (unsigned short*)(w + 48 * MB);
    unsigned short* Wql = (unsigned short*)(w + 50 * MB);
    unsigned short* Wkh = (unsigned short*)(w + 52 * MB);
    unsigned short* Wkl = (unsigned short*)(w + 54 * MB);
    unsigned short* Wvh = (unsigned short*)(w + 56 * MB);
    unsigned short* Wvl = (unsigned short*)(w + 58 * MB);

    const int NW8 = (D_MODEL * D_MODEL) / 8;      // 131072

    // pre-split the 3 weight matrices (removes 32x-redundant in-loop W conversion)
    conv_w<<<(3 * NW8) / 256, 256, 0, stream>>>(Wq, Wk, Wv, Wqh, Wql, Wkh, Wkl, Wvh, Wvl);

    // fused Q/K/V: grid (32,8,3), x=bm -> id%8 = bm%8 (A-row XCD locality)
    proj_qkv<<<dim3(32, 8, 3), 256, 0, stream>>>(q, k, v,
                                                 Wqh, Wql, Wkh, Wkl, Wvh, Wvl,
                                                 bq, bk, bv, qp, kp, vt);

    // bh on x: all 8 q-blocks of a (b,h) share an XCD (id%8 = bh%8)
    attn_mfma<<<dim3(BATCH * N_HEADS, SEQ / 128), 256, 0, stream>>>(qp, kp, vt, ctxh);

    proj_o<<<dim3(32, 8), 256, 0, stream>>>(ctxh, Wo, bo, out);
}